// Round 2
// baseline (920.635 us; speedup 1.0000x reference)
//
#include <hip/hip_runtime.h>
#include <math.h>

static constexpr int NN = 100000;   // nodes
static constexpr int NE = 1600000;  // edges
static constexpr int NB_SCAN = (NN + 1023) / 1024;  // 98 scan blocks

// ---------------- utility ----------------
__global__ __launch_bounds__(256) void k_zero(unsigned* __restrict__ p, int n) {
  int i = blockIdx.x * 256 + threadIdx.x;
  if (i < n) p[i] = 0u;
}

// Packed degree count: low16 = all-edge count, high16 = st (rev==0) count.
__global__ __launch_bounds__(256) void k_deg(const int* __restrict__ dst,
                                             const int* __restrict__ rev,
                                             unsigned* __restrict__ cnt) {
  int e = blockIdx.x * 256 + threadIdx.x;
  if (e >= NE) return;
  unsigned add = 1u + ((rev[e] == 0) ? 0x10000u : 0u);
  atomicAdd(&cnt[dst[e]], add);
}

// ---------------- 3-kernel exclusive scan of (cnt & 0xFFFF) ----------------
__global__ __launch_bounds__(256) void k_scan1(const unsigned* __restrict__ cnt,
                                               unsigned* __restrict__ bsums) {
  int g = blockIdx.x, t = threadIdx.x;
  int base = g * 1024 + t * 4;
  unsigned s = 0;
  #pragma unroll
  for (int j = 0; j < 4; ++j) {
    int i = base + j;
    if (i < NN) s += cnt[i] & 0xFFFFu;
  }
  __shared__ unsigned sm[256];
  sm[t] = s;
  __syncthreads();
  for (int o = 128; o > 0; o >>= 1) {
    if (t < o) sm[t] += sm[t + o];
    __syncthreads();
  }
  if (t == 0) bsums[g] = sm[0];
}

__global__ void k_scan2(unsigned* __restrict__ bsums) {
  if (threadIdx.x == 0 && blockIdx.x == 0) {
    unsigned run = 0;
    for (int i = 0; i < NB_SCAN; ++i) {
      unsigned v = bsums[i];
      bsums[i] = run;
      run += v;
    }
  }
}

__global__ __launch_bounds__(256) void k_scan3(const unsigned* __restrict__ cnt,
                                               const unsigned* __restrict__ bsums,
                                               unsigned* __restrict__ roff,
                                               unsigned* __restrict__ cursor) {
  int g = blockIdx.x, t = threadIdx.x;
  int base = g * 1024 + t * 4;
  unsigned v[4];
  unsigned tsum = 0;
  #pragma unroll
  for (int j = 0; j < 4; ++j) {
    int i = base + j;
    v[j] = (i < NN) ? (cnt[i] & 0xFFFFu) : 0u;
    tsum += v[j];
  }
  __shared__ unsigned sm[256];
  sm[t] = tsum;
  __syncthreads();
  for (int o = 1; o < 256; o <<= 1) {
    unsigned u = (t >= o) ? sm[t - o] : 0u;
    __syncthreads();
    sm[t] += u;
    __syncthreads();
  }
  unsigned run = bsums[g] + sm[t] - tsum;  // exclusive prefix for this thread
  #pragma unroll
  for (int j = 0; j < 4; ++j) {
    int i = base + j;
    if (i < NN) {
      roff[i] = run;
      cursor[i] = run;
      run += v[j];
      if (i == NN - 1) roff[NN] = run;
    }
  }
}

// dinv4[n] = {rsqrt(deg_st), rsqrt(deg_ts), rsqrt(deg_all), 0}; dinvA separate.
__global__ __launch_bounds__(256) void k_dinv(const unsigned* __restrict__ cnt,
                                              float4* __restrict__ dinv4,
                                              float* __restrict__ dinvA) {
  int n = blockIdx.x * 256 + threadIdx.x;
  if (n >= NN) return;
  unsigned c = cnt[n];
  float all = (float)(c & 0xFFFFu) + 1.0f;
  float st = (float)(c >> 16) + 1.0f;
  float ts = all - st + 1.0f;  // (all-1) - (st-1) + 1
  float da = rsqrtf(all);
  dinv4[n] = make_float4(rsqrtf(st), rsqrtf(ts), da, 0.0f);
  dinvA[n] = da;
}

// CSR fill: col[pos] = src | (rev << 31)
__global__ __launch_bounds__(256) void k_csr(const int* __restrict__ src,
                                             const int* __restrict__ dst,
                                             const int* __restrict__ rev,
                                             unsigned* __restrict__ cursor,
                                             unsigned* __restrict__ col) {
  int e = blockIdx.x * 256 + threadIdx.x;
  if (e >= NE) return;
  unsigned p = atomicAdd(&cursor[dst[e]], 1u);
  col[p] = (unsigned)src[e] | (rev[e] ? 0x80000000u : 0u);
}

// Concatenate [W_st | W_ts | W1] -> Wcat[128][192]
__global__ __launch_bounds__(256) void k_packW(const float* __restrict__ Wst,
                                               const float* __restrict__ Wts,
                                               const float* __restrict__ W1,
                                               float* __restrict__ Wcat) {
  int i = blockIdx.x * 256 + threadIdx.x;
  if (i >= 128 * 192) return;
  int k = i / 192, c = i % 192;
  float v = (c < 64) ? Wst[k * 64 + c]
          : (c < 128) ? Wts[k * 64 + (c - 64)]
                      : W1[k * 64 + (c - 128)];
  Wcat[i] = v;
}

// ---------------- tall-skinny fp32 GEMM: O[N,NC] = A[N,K] @ W[K,NC] ----------------
// Thread computes 8 rows x 4 cols. W rows read as float4 (coalesced across cg),
// A rows broadcast within the wave.
template <int K, int NC>
__global__ __launch_bounds__(256) void k_gemm(const float* __restrict__ A,
                                              const float* __restrict__ W,
                                              float* __restrict__ O) {
  constexpr int CG = NC / 4;
  int gx = blockIdx.x * 256 + threadIdx.x;
  int rb = gx / CG;
  int cg = gx % CG;
  int r0 = rb * 8;
  if (r0 >= NN) return;
  int cc = cg * 4;
  float acc[8][4] = {};
  const float4* A4 = (const float4*)A;
  for (int k = 0; k < K; k += 4) {
    float w[4][4];
    #pragma unroll
    for (int j = 0; j < 4; ++j) {
      float4 t = *(const float4*)(W + (size_t)(k + j) * NC + cc);
      w[j][0] = t.x; w[j][1] = t.y; w[j][2] = t.z; w[j][3] = t.w;
    }
    #pragma unroll
    for (int i = 0; i < 8; ++i) {
      float4 xv = A4[(size_t)(r0 + i) * (K / 4) + (k >> 2)];
      float xa[4] = {xv.x, xv.y, xv.z, xv.w};
      #pragma unroll
      for (int c = 0; c < 4; ++c)
        #pragma unroll
        for (int j = 0; j < 4; ++j)
          acc[i][c] = fmaf(xa[j], w[j][c], acc[i][c]);
    }
  }
  #pragma unroll
  for (int i = 0; i < 8; ++i) {
    float4 o = make_float4(acc[i][0], acc[i][1], acc[i][2], acc[i][3]);
    *(float4*)(O + (size_t)(r0 + i) * NC + cc) = o;
  }
}

// ---------------- layer-1 aggregation: 192 cols, 3 masks, +bias +ReLU ----------------
// One wave per node; lane handles cols {lane, lane+64, lane+128}.
// Per edge only the "all" block plus ONE of st/ts blocks is read (masks complementary).
// Edge loop unrolled x2: two independent gather chains in flight per wave.
__global__ __launch_bounds__(256) void k_agg1(const unsigned* __restrict__ roff,
                                              const unsigned* __restrict__ col,
                                              const float4* __restrict__ dinv4,
                                              const float* __restrict__ H,
                                              const float* __restrict__ bst,
                                              const float* __restrict__ bts,
                                              const float* __restrict__ b1,
                                              float* __restrict__ h1) {
  int wid = threadIdx.x >> 6;
  int lane = threadIdx.x & 63;
  int d = blockIdx.x * 4 + wid;
  if (d >= NN) return;
  unsigned ro = roff[d], re = roff[d + 1];
  float4 dv = dinv4[d];
  float a0 = 0.f, a1 = 0.f, a2 = 0.f;
  unsigned i = ro;
  for (; i + 2 <= re; i += 2) {
    unsigned c0 = col[i];
    unsigned c1 = col[i + 1];
    unsigned s0 = c0 & 0x7FFFFFFFu;
    unsigned s1 = c1 & 0x7FFFFFFFu;
    float4 sv0 = dinv4[s0];
    float4 sv1 = dinv4[s1];
    const float* Hs0 = H + (size_t)s0 * 192;
    const float* Hs1 = H + (size_t)s1 * 192;
    float hA0 = Hs0[128 + lane];
    float hA1 = Hs1[128 + lane];
    float hB0 = (c0 & 0x80000000u) ? Hs0[64 + lane] : Hs0[lane];
    float hB1 = (c1 & 0x80000000u) ? Hs1[64 + lane] : Hs1[lane];
    a2 = fmaf(sv0.z * dv.z, hA0, a2);
    a2 = fmaf(sv1.z * dv.z, hA1, a2);
    if (!(c0 & 0x80000000u)) a0 = fmaf(sv0.x * dv.x, hB0, a0);
    else                     a1 = fmaf(sv0.y * dv.y, hB0, a1);
    if (!(c1 & 0x80000000u)) a0 = fmaf(sv1.x * dv.x, hB1, a0);
    else                     a1 = fmaf(sv1.y * dv.y, hB1, a1);
  }
  for (; i < re; ++i) {
    unsigned c = col[i];
    unsigned s = c & 0x7FFFFFFFu;
    float4 sv = dinv4[s];
    const float* Hs = H + (size_t)s * 192;
    a2 = fmaf(sv.z * dv.z, Hs[128 + lane], a2);
    if (!(c & 0x80000000u)) a0 = fmaf(sv.x * dv.x, Hs[lane], a0);
    else                    a1 = fmaf(sv.y * dv.y, Hs[64 + lane], a1);
  }
  const float* Hd = H + (size_t)d * 192;
  a0 = fmaf(dv.x * dv.x, Hd[lane], a0) + bst[lane];
  a1 = fmaf(dv.y * dv.y, Hd[64 + lane], a1) + bts[lane];
  a2 = fmaf(dv.z * dv.z, Hd[128 + lane], a2) + b1[lane];
  float* o = h1 + (size_t)d * 192;
  o[lane] = fmaxf(a0, 0.f);
  o[64 + lane] = fmaxf(a1, 0.f);
  o[128 + lane] = fmaxf(a2, 0.f);
}

// ---------------- layer-2 aggregation: 128 cols, all-mask, +bias ----------------
__global__ __launch_bounds__(256) void k_agg2(const unsigned* __restrict__ roff,
                                              const unsigned* __restrict__ col,
                                              const float* __restrict__ dinvA,
                                              const float* __restrict__ T,
                                              const float* __restrict__ b2,
                                              float* __restrict__ h2) {
  int wid = threadIdx.x >> 6;
  int lane = threadIdx.x & 63;
  int d = blockIdx.x * 4 + wid;
  if (d >= NN) return;
  unsigned ro = roff[d], re = roff[d + 1];
  float da = dinvA[d];
  float a0 = 0.f, a1 = 0.f;
  unsigned i = ro;
  for (; i + 2 <= re; i += 2) {
    unsigned s0 = col[i] & 0x7FFFFFFFu;
    unsigned s1 = col[i + 1] & 0x7FFFFFFFu;
    float cf0 = dinvA[s0] * da;
    float cf1 = dinvA[s1] * da;
    const float* Ts0 = T + (size_t)s0 * 128;
    const float* Ts1 = T + (size_t)s1 * 128;
    float t00 = Ts0[lane], t01 = Ts0[64 + lane];
    float t10 = Ts1[lane], t11 = Ts1[64 + lane];
    a0 = fmaf(cf0, t00, a0);
    a1 = fmaf(cf0, t01, a1);
    a0 = fmaf(cf1, t10, a0);
    a1 = fmaf(cf1, t11, a1);
  }
  for (; i < re; ++i) {
    unsigned s = col[i] & 0x7FFFFFFFu;
    float cf = dinvA[s] * da;
    const float* Ts = T + (size_t)s * 128;
    a0 = fmaf(cf, Ts[lane], a0);
    a1 = fmaf(cf, Ts[64 + lane], a1);
  }
  const float* Td = T + (size_t)d * 128;
  a0 = fmaf(da * da, Td[lane], a0) + b2[lane];
  a1 = fmaf(da * da, Td[64 + lane], a1) + b2[64 + lane];
  float* o = h2 + (size_t)d * 128;
  o[lane] = a0;
  o[64 + lane] = a1;
}

// ---------------- layer-3 aggregation + log_softmax: 16 cols ----------------
// 16-lane groups; one group per node.
__global__ __launch_bounds__(256) void k_agg3(const unsigned* __restrict__ roff,
                                              const unsigned* __restrict__ col,
                                              const float* __restrict__ dinvA,
                                              const float* __restrict__ T,
                                              const float* __restrict__ b3,
                                              float* __restrict__ out) {
  int g = threadIdx.x >> 4;
  int l = threadIdx.x & 15;
  int d = blockIdx.x * 16 + g;
  if (d >= NN) return;
  unsigned ro = roff[d], re = roff[d + 1];
  float da = dinvA[d];
  float a = 0.f;
  for (unsigned i = ro; i < re; ++i) {
    unsigned s = col[i] & 0x7FFFFFFFu;
    a = fmaf(dinvA[s] * da, T[(size_t)s * 16 + l], a);
  }
  a = fmaf(da * da, T[(size_t)d * 16 + l], a) + b3[l];
  // log_softmax over the 16 lanes of this group
  float m = a;
  #pragma unroll
  for (int o = 8; o > 0; o >>= 1) m = fmaxf(m, __shfl_xor(m, o, 16));
  float ex = expf(a - m);
  float sm = ex;
  #pragma unroll
  for (int o = 8; o > 0; o >>= 1) sm += __shfl_xor(sm, o, 16);
  out[(size_t)d * 16 + l] = a - m - logf(sm);
}

// ---------------- host-side launch ----------------
extern "C" void kernel_launch(void* const* d_in, const int* in_sizes, int n_in,
                              void* d_out, int out_size, void* d_ws, size_t ws_size,
                              hipStream_t stream) {
  const float* x   = (const float*)d_in[0];
  const int* ei    = (const int*)d_in[1];
  const int* srcp  = ei;
  const int* dstp  = ei + NE;
  const int* revp  = (const int*)d_in[2];
  const float* Wst = (const float*)d_in[3];
  const float* bst = (const float*)d_in[4];
  const float* Wts = (const float*)d_in[5];
  const float* bts = (const float*)d_in[6];
  const float* W1  = (const float*)d_in[7];
  const float* b1  = (const float*)d_in[8];
  const float* W2  = (const float*)d_in[9];
  const float* b2  = (const float*)d_in[10];
  const float* W3  = (const float*)d_in[11];
  const float* b3  = (const float*)d_in[12];
  float* out = (float*)d_out;

  char* ws = (char*)d_ws;
  size_t off = 0;
  auto alloc = [&](size_t bytes) -> void* {
    off = (off + 255) & ~size_t(255);
    void* p = ws + off;
    off += bytes;
    return p;
  };
  unsigned* cnt    = (unsigned*)alloc(sizeof(unsigned) * NN);
  unsigned* roff   = (unsigned*)alloc(sizeof(unsigned) * (NN + 1));
  unsigned* cursor = (unsigned*)alloc(sizeof(unsigned) * NN);
  unsigned* bsums  = (unsigned*)alloc(sizeof(unsigned) * 128);
  float*    Wcat   = (float*)alloc(sizeof(float) * 128 * 192);
  unsigned* col    = (unsigned*)alloc(sizeof(unsigned) * NE);
  float4*   dinv4  = (float4*)alloc(sizeof(float4) * NN);
  float*    dinvA  = (float*)alloc(sizeof(float) * NN);
  float*    bufA   = (float*)alloc(sizeof(float) * (size_t)NN * 192);
  float*    bufB   = (float*)alloc(sizeof(float) * (size_t)NN * 192);
  (void)ws_size; (void)in_sizes; (void)n_in; (void)out_size;

  const int nbN = (NN + 255) / 256;      // 391
  const int nbE = (NE + 255) / 256;      // 6250

  // CSR + degree build
  hipLaunchKernelGGL(k_zero, dim3(nbN), dim3(256), 0, stream, cnt, NN);
  hipLaunchKernelGGL(k_deg, dim3(nbE), dim3(256), 0, stream, dstp, revp, cnt);
  hipLaunchKernelGGL(k_scan1, dim3(NB_SCAN), dim3(256), 0, stream, cnt, bsums);
  hipLaunchKernelGGL(k_scan2, dim3(1), dim3(64), 0, stream, bsums);
  hipLaunchKernelGGL(k_scan3, dim3(NB_SCAN), dim3(256), 0, stream, cnt, bsums, roff, cursor);
  hipLaunchKernelGGL(k_dinv, dim3(nbN), dim3(256), 0, stream, cnt, dinv4, dinvA);
  hipLaunchKernelGGL(k_csr, dim3(nbE), dim3(256), 0, stream, srcp, dstp, revp, cursor, col);
  hipLaunchKernelGGL(k_packW, dim3((128 * 192 + 255) / 256), dim3(256), 0, stream,
                     Wst, Wts, W1, Wcat);

  // Layer 1: H = x @ Wcat  [N,192]  -> bufA ; aggregate+bias+relu -> bufB (h1)
  {
    int threads = (NN / 8) * (192 / 4);
    hipLaunchKernelGGL((k_gemm<128, 192>), dim3((threads + 255) / 256), dim3(256), 0, stream,
                       x, Wcat, bufA);
  }
  hipLaunchKernelGGL(k_agg1, dim3(NN / 4), dim3(256), 0, stream,
                     roff, col, dinv4, bufA, bst, bts, b1, bufB);

  // Layer 2: T2 = h1 @ W2 [N,128] -> bufA ; aggregate+bias -> bufB (h2)
  {
    int threads = (NN / 8) * (128 / 4);
    hipLaunchKernelGGL((k_gemm<192, 128>), dim3((threads + 255) / 256), dim3(256), 0, stream,
                       bufB, W2, bufA);
  }
  hipLaunchKernelGGL(k_agg2, dim3(NN / 4), dim3(256), 0, stream,
                     roff, col, dinvA, bufA, b2, bufB);

  // Layer 3: T3 = h2 @ W3 [N,16] -> bufA ; aggregate+bias+log_softmax -> out
  {
    int threads = (NN / 8) * (16 / 4);
    hipLaunchKernelGGL((k_gemm<128, 16>), dim3((threads + 255) / 256), dim3(256), 0, stream,
                       bufB, W3, bufA);
  }
  hipLaunchKernelGGL(k_agg3, dim3(NN / 16), dim3(256), 0, stream,
                     roff, col, dinvA, bufA, b3, out);
}

// Round 7
// 803.674 us; speedup vs baseline: 1.1455x; 1.1455x over previous
//
#include <hip/hip_runtime.h>
#include <math.h>

static constexpr int NN = 100000;   // nodes
static constexpr int NE = 1600000;  // edges
static constexpr int NB_SCAN = (NN + 1023) / 1024;  // 98 scan blocks

// ---------------- bf16 helpers (fp32 <-> bf16 bit ops) ----------------
__device__ __forceinline__ float bflo(unsigned u) { return __uint_as_float(u << 16); }
__device__ __forceinline__ float bfhi(unsigned u) { return __uint_as_float(u & 0xFFFF0000u); }
__device__ __forceinline__ unsigned packbf2(float a, float b) {  // RTNE
  unsigned ua = __float_as_uint(a), ub = __float_as_uint(b);
  unsigned ra = (ua + 0x7fffu + ((ua >> 16) & 1u)) >> 16;
  unsigned rb = (ub + 0x7fffu + ((ub >> 16) & 1u)) >> 16;
  return ra | (rb << 16);
}

// ---------------- utility ----------------
__global__ __launch_bounds__(256) void k_zero(unsigned* __restrict__ p, int n) {
  int i = blockIdx.x * 256 + threadIdx.x;
  if (i < n) p[i] = 0u;
}

// Packed degree count: low16 = all-edge count, high16 = st (rev==0) count.
__global__ __launch_bounds__(256) void k_deg(const int* __restrict__ dst,
                                             const int* __restrict__ rev,
                                             unsigned* __restrict__ cnt) {
  int e = blockIdx.x * 256 + threadIdx.x;
  if (e >= NE) return;
  unsigned add = 1u + ((rev[e] == 0) ? 0x10000u : 0u);
  atomicAdd(&cnt[dst[e]], add);
}

// ---------------- scan of (cnt & 0xFFFF) ----------------
__global__ __launch_bounds__(256) void k_scan1(const unsigned* __restrict__ cnt,
                                               unsigned* __restrict__ bsums) {
  int g = blockIdx.x, t = threadIdx.x;
  int base = g * 1024 + t * 4;
  unsigned s = 0;
  #pragma unroll
  for (int j = 0; j < 4; ++j) {
    int i = base + j;
    if (i < NN) s += cnt[i] & 0xFFFFu;
  }
  __shared__ unsigned sm[256];
  sm[t] = s;
  __syncthreads();
  for (int o = 128; o > 0; o >>= 1) {
    if (t < o) sm[t] += sm[t + o];
    __syncthreads();
  }
  if (t == 0) bsums[g] = sm[0];
}

__global__ __launch_bounds__(128) void k_scan2(unsigned* __restrict__ bsums) {
  __shared__ unsigned sm[128];
  int t = threadIdx.x;
  unsigned v = (t < NB_SCAN) ? bsums[t] : 0u;
  sm[t] = v;
  __syncthreads();
  for (int o = 1; o < 128; o <<= 1) {
    unsigned u = (t >= o) ? sm[t - o] : 0u;
    __syncthreads();
    sm[t] += u;
    __syncthreads();
  }
  if (t < NB_SCAN) bsums[t] = sm[t] - v;  // exclusive
}

__global__ __launch_bounds__(256) void k_scan3(const unsigned* __restrict__ cnt,
                                               const unsigned* __restrict__ bsums,
                                               unsigned* __restrict__ roff,
                                               unsigned* __restrict__ cursor) {
  int g = blockIdx.x, t = threadIdx.x;
  int base = g * 1024 + t * 4;
  unsigned v[4];
  unsigned tsum = 0;
  #pragma unroll
  for (int j = 0; j < 4; ++j) {
    int i = base + j;
    v[j] = (i < NN) ? (cnt[i] & 0xFFFFu) : 0u;
    tsum += v[j];
  }
  __shared__ unsigned sm[256];
  sm[t] = tsum;
  __syncthreads();
  for (int o = 1; o < 256; o <<= 1) {
    unsigned u = (t >= o) ? sm[t - o] : 0u;
    __syncthreads();
    sm[t] += u;
    __syncthreads();
  }
  unsigned run = bsums[g] + sm[t] - tsum;  // exclusive prefix for this thread
  #pragma unroll
  for (int j = 0; j < 4; ++j) {
    int i = base + j;
    if (i < NN) {
      roff[i] = run;
      cursor[i] = run;
      run += v[j];
      if (i == NN - 1) roff[NN] = run;
    }
  }
}

// dinv4[n] = {rsqrt(deg_st), rsqrt(deg_ts), rsqrt(deg_all), 0}
__global__ __launch_bounds__(256) void k_dinv(const unsigned* __restrict__ cnt,
                                              float4* __restrict__ dinv4) {
  int n = blockIdx.x * 256 + threadIdx.x;
  if (n >= NN) return;
  unsigned c = cnt[n];
  float all = (float)(c & 0xFFFFu) + 1.0f;
  float st = (float)(c >> 16) + 1.0f;
  float ts = all - st + 1.0f;
  dinv4[n] = make_float4(rsqrtf(st), rsqrtf(ts), rsqrtf(all), 0.0f);
}

// CSR fill with precomputed per-edge coefficients:
// ecsr[p] = {src | rev<<31, bits(cB), bits(cAll), 0}
__global__ __launch_bounds__(256) void k_csr(const int* __restrict__ src,
                                             const int* __restrict__ dst,
                                             const int* __restrict__ rev,
                                             const float4* __restrict__ dinv4,
                                             unsigned* __restrict__ cursor,
                                             uint4* __restrict__ ecsr) {
  int e = blockIdx.x * 256 + threadIdx.x;
  if (e >= NE) return;
  int s = src[e], d = dst[e];
  int r = rev[e];
  float4 sv = dinv4[s];
  float4 dv = dinv4[d];
  float cB = r ? (sv.y * dv.y) : (sv.x * dv.x);
  float cA = sv.z * dv.z;
  unsigned p = atomicAdd(&cursor[d], 1u);
  ecsr[p] = make_uint4((unsigned)s | (r ? 0x80000000u : 0u),
                       __float_as_uint(cB), __float_as_uint(cA), 0u);
}

// Wcat logical layout [st(0-63) | all(64-127) | ts(128-191)]
__global__ __launch_bounds__(256) void k_packW(const float* __restrict__ Wst,
                                               const float* __restrict__ Wts,
                                               const float* __restrict__ W1,
                                               float* __restrict__ Wcat) {
  int i = blockIdx.x * 256 + threadIdx.x;
  if (i >= 128 * 192) return;
  int k = i / 192, c = i % 192;
  float v = (c < 64)  ? Wst[k * 64 + c]
          : (c < 128) ? W1[k * 64 + (c - 64)]
                      : Wts[k * 64 + (c - 128)];
  Wcat[i] = v;
}

// ---------------- tall-skinny GEMM: O[N,NC] = A[N,K] @ W[K,NC] ----------------
// AB16: 0 = fp32 A, 1 = bf16 A.  OM: 0 = fp32 out, 1 = bf16 out,
// 2 = bf16 out with dup layout [st|all|ts|all] (row stride 256, dup cols 64-127 -> 192-255).
template <int K, int NC, int AB16, int OM>
__global__ __launch_bounds__(256) void k_gemm(const void* __restrict__ Ap,
                                              const float* __restrict__ W,
                                              void* __restrict__ Op) {
  constexpr int CG = NC / 4;
  int gx = blockIdx.x * 256 + threadIdx.x;
  int rb = gx / CG;
  int cg = gx % CG;
  int r0 = rb * 8;
  if (r0 >= NN) return;
  int cc = cg * 4;
  float acc[8][4] = {};
  if constexpr (AB16 == 0) {
    const float4* A4 = (const float4*)Ap;
    for (int k = 0; k < K; k += 4) {
      float w[4][4];
      #pragma unroll
      for (int j = 0; j < 4; ++j) {
        float4 t = *(const float4*)(W + (size_t)(k + j) * NC + cc);
        w[j][0] = t.x; w[j][1] = t.y; w[j][2] = t.z; w[j][3] = t.w;
      }
      #pragma unroll
      for (int i = 0; i < 8; ++i) {
        float4 xv = A4[(size_t)(r0 + i) * (K / 4) + (k >> 2)];
        float xa[4] = {xv.x, xv.y, xv.z, xv.w};
        #pragma unroll
        for (int c = 0; c < 4; ++c)
          #pragma unroll
          for (int j = 0; j < 4; ++j)
            acc[i][c] = fmaf(xa[j], w[j][c], acc[i][c]);
      }
    }
  } else {
    const uint4* A4 = (const uint4*)Ap;
    for (int k = 0; k < K; k += 8) {
      float w[8][4];
      #pragma unroll
      for (int j = 0; j < 8; ++j) {
        float4 t = *(const float4*)(W + (size_t)(k + j) * NC + cc);
        w[j][0] = t.x; w[j][1] = t.y; w[j][2] = t.z; w[j][3] = t.w;
      }
      #pragma unroll
      for (int i = 0; i < 8; ++i) {
        uint4 ua = A4[(size_t)(r0 + i) * (K / 8) + (k >> 3)];
        float xa[8] = {bflo(ua.x), bfhi(ua.x), bflo(ua.y), bfhi(ua.y),
                       bflo(ua.z), bfhi(ua.z), bflo(ua.w), bfhi(ua.w)};
        #pragma unroll
        for (int c = 0; c < 4; ++c)
          #pragma unroll
          for (int j = 0; j < 8; ++j)
            acc[i][c] = fmaf(xa[j], w[j][c], acc[i][c]);
      }
    }
  }
  if constexpr (OM == 0) {
    float* O = (float*)Op;
    #pragma unroll
    for (int i = 0; i < 8; ++i) {
      float4 o = make_float4(acc[i][0], acc[i][1], acc[i][2], acc[i][3]);
      *(float4*)(O + (size_t)(r0 + i) * NC + cc) = o;
    }
  } else if constexpr (OM == 1) {
    char* O = (char*)Op;
    #pragma unroll
    for (int i = 0; i < 8; ++i) {
      uint2 p;
      p.x = packbf2(acc[i][0], acc[i][1]);
      p.y = packbf2(acc[i][2], acc[i][3]);
      *(uint2*)(O + ((size_t)(r0 + i) * NC + cc) * 2) = p;
    }
  } else {
    char* O = (char*)Op;
    #pragma unroll
    for (int i = 0; i < 8; ++i) {
      uint2 p;
      p.x = packbf2(acc[i][0], acc[i][1]);
      p.y = packbf2(acc[i][2], acc[i][3]);
      *(uint2*)(O + ((size_t)(r0 + i) * 256 + cc) * 2) = p;
      if (cc >= 64 && cc < 128)
        *(uint2*)(O + ((size_t)(r0 + i) * 256 + cc + 128) * 2) = p;
    }
  }
}

// ---------------- layer-1 aggregation ----------------
// H' rows: 256 bf16 = 128 uints: half0 = [st|all], half1 = [ts|all].
// Per edge ONE 256B load: lanes 0-31 -> B-block (st or ts), lanes 32-63 -> all.
// h1 out: bf16 [N,192] = 96 uints/row, layout [st|ts|all].
__global__ __launch_bounds__(256) void k_agg1(const unsigned* __restrict__ roff,
                                              const uint4* __restrict__ ecsr,
                                              const float4* __restrict__ dinv4,
                                              const unsigned* __restrict__ Hb,
                                              const float* __restrict__ bst,
                                              const float* __restrict__ bts,
                                              const float* __restrict__ b1,
                                              unsigned* __restrict__ h1) {
  int wid = threadIdx.x >> 6;
  int lane = threadIdx.x & 63;
  int d = blockIdx.x * 4 + wid;
  if (d >= NN) return;
  unsigned ro = roff[d], re = roff[d + 1];
  bool loB = lane < 32;
  float s0l = 0.f, s0h = 0.f, s1l = 0.f, s1h = 0.f, s2l = 0.f, s2h = 0.f;
  unsigned i = ro;
  for (; i + 2 <= re; i += 2) {
    uint4 e0 = ecsr[i];
    uint4 e1 = ecsr[i + 1];
    unsigned s0 = e0.x & 0x7FFFFFFFu, h0 = e0.x >> 31;
    unsigned s1 = e1.x & 0x7FFFFFFFu, h1b = e1.x >> 31;
    unsigned u0 = Hb[(size_t)s0 * 128 + h0 * 64 + lane];
    unsigned u1 = Hb[(size_t)s1 * 128 + h1b * 64 + lane];
    float c0 = loB ? __uint_as_float(e0.y) : __uint_as_float(e0.z);
    float c1 = loB ? __uint_as_float(e1.y) : __uint_as_float(e1.z);
    float a0l = c0 * bflo(u0), a0h = c0 * bfhi(u0);
    float a1l = c1 * bflo(u1), a1h = c1 * bfhi(u1);
    if (!loB)      { s2l += a0l; s2h += a0h; }
    else if (!h0)  { s0l += a0l; s0h += a0h; }
    else           { s1l += a0l; s1h += a0h; }
    if (!loB)      { s2l += a1l; s2h += a1h; }
    else if (!h1b) { s0l += a1l; s0h += a1h; }
    else           { s1l += a1l; s1h += a1h; }
  }
  for (; i < re; ++i) {
    uint4 e = ecsr[i];
    unsigned s = e.x & 0x7FFFFFFFu, h = e.x >> 31;
    unsigned u = Hb[(size_t)s * 128 + h * 64 + lane];
    float c = loB ? __uint_as_float(e.y) : __uint_as_float(e.z);
    float al = c * bflo(u), ah = c * bfhi(u);
    if (!loB)     { s2l += al; s2h += ah; }
    else if (!h)  { s0l += al; s0h += ah; }
    else          { s1l += al; s1h += ah; }
  }
  float4 dv = dinv4[d];
  unsigned u0 = Hb[(size_t)d * 128 + lane];        // half0: st | all
  unsigned u1 = Hb[(size_t)d * 128 + 64 + lane];   // half1: ts | all(dup)
  if (loB) {
    float rs = dv.x * dv.x, rt = dv.y * dv.y;
    s0l = fmaf(rs, bflo(u0), s0l); s0h = fmaf(rs, bfhi(u0), s0h);
    s1l = fmaf(rt, bflo(u1), s1l); s1h = fmaf(rt, bfhi(u1), s1h);
    float2 bs = ((const float2*)bst)[lane];
    float2 bt = ((const float2*)bts)[lane];
    s0l = fmaxf(s0l + bs.x, 0.f); s0h = fmaxf(s0h + bs.y, 0.f);
    s1l = fmaxf(s1l + bt.x, 0.f); s1h = fmaxf(s1h + bt.y, 0.f);
    h1[(size_t)d * 96 + lane] = packbf2(s0l, s0h);         // st cols 2l,2l+1
    h1[(size_t)d * 96 + 32 + lane] = packbf2(s1l, s1h);    // ts cols 64+2l
  } else {
    float ra = dv.z * dv.z;
    s2l = fmaf(ra, bflo(u0), s2l); s2h = fmaf(ra, bfhi(u0), s2h);
    float2 bb = ((const float2*)b1)[lane - 32];
    s2l = fmaxf(s2l + bb.x, 0.f); s2h = fmaxf(s2h + bb.y, 0.f);
    h1[(size_t)d * 96 + 64 + (lane - 32)] = packbf2(s2l, s2h);  // all cols 128+..
  }
}

// ---------------- layer-2 aggregation: T2' bf16 [N,128] = 64 uints/row ----------------
__global__ __launch_bounds__(256) void k_agg2(const unsigned* __restrict__ roff,
                                              const uint4* __restrict__ ecsr,
                                              const float4* __restrict__ dinv4,
                                              const unsigned* __restrict__ Tb,
                                              const float* __restrict__ b2,
                                              unsigned* __restrict__ h2) {
  int wid = threadIdx.x >> 6;
  int lane = threadIdx.x & 63;
  int d = blockIdx.x * 4 + wid;
  if (d >= NN) return;
  unsigned ro = roff[d], re = roff[d + 1];
  float sl = 0.f, sh = 0.f;
  unsigned i = ro;
  for (; i + 2 <= re; i += 2) {
    uint4 e0 = ecsr[i];
    uint4 e1 = ecsr[i + 1];
    unsigned s0 = e0.x & 0x7FFFFFFFu;
    unsigned s1 = e1.x & 0x7FFFFFFFu;
    unsigned u0 = Tb[(size_t)s0 * 64 + lane];
    unsigned u1 = Tb[(size_t)s1 * 64 + lane];
    float c0 = __uint_as_float(e0.z);
    float c1 = __uint_as_float(e1.z);
    sl = fmaf(c0, bflo(u0), sl); sh = fmaf(c0, bfhi(u0), sh);
    sl = fmaf(c1, bflo(u1), sl); sh = fmaf(c1, bfhi(u1), sh);
  }
  for (; i < re; ++i) {
    uint4 e = ecsr[i];
    unsigned s = e.x & 0x7FFFFFFFu;
    unsigned u = Tb[(size_t)s * 64 + lane];
    float c = __uint_as_float(e.z);
    sl = fmaf(c, bflo(u), sl); sh = fmaf(c, bfhi(u), sh);
  }
  float dz = dinv4[d].z;
  float ra = dz * dz;
  unsigned u = Tb[(size_t)d * 64 + lane];
  sl = fmaf(ra, bflo(u), sl); sh = fmaf(ra, bfhi(u), sh);
  float2 bb = ((const float2*)b2)[lane];
  sl += bb.x; sh += bb.y;
  h2[(size_t)d * 64 + lane] = packbf2(sl, sh);
}

// ---------------- layer-3 aggregation + log_softmax: T3 fp32 [N,16] ----------------
__global__ __launch_bounds__(256) void k_agg3(const unsigned* __restrict__ roff,
                                              const uint4* __restrict__ ecsr,
                                              const float4* __restrict__ dinv4,
                                              const float* __restrict__ T,
                                              const float* __restrict__ b3,
                                              float* __restrict__ out) {
  int g = threadIdx.x >> 4;
  int l = threadIdx.x & 15;
  int d = blockIdx.x * 16 + g;
  if (d >= NN) return;
  unsigned ro = roff[d], re = roff[d + 1];
  float a = 0.f;
  for (unsigned i = ro; i < re; ++i) {
    uint4 e = ecsr[i];
    unsigned s = e.x & 0x7FFFFFFFu;
    a = fmaf(__uint_as_float(e.z), T[(size_t)s * 16 + l], a);
  }
  float dz = dinv4[d].z;
  a = fmaf(dz * dz, T[(size_t)d * 16 + l], a) + b3[l];
  float m = a;
  #pragma unroll
  for (int o = 8; o > 0; o >>= 1) m = fmaxf(m, __shfl_xor(m, o, 16));
  float ex = expf(a - m);
  float sm = ex;
  #pragma unroll
  for (int o = 8; o > 0; o >>= 1) sm += __shfl_xor(sm, o, 16);
  out[(size_t)d * 16 + l] = a - m - logf(sm);
}

// ---------------- host-side launch ----------------
extern "C" void kernel_launch(void* const* d_in, const int* in_sizes, int n_in,
                              void* d_out, int out_size, void* d_ws, size_t ws_size,
                              hipStream_t stream) {
  const float* x   = (const float*)d_in[0];
  const int* ei    = (const int*)d_in[1];
  const int* srcp  = ei;
  const int* dstp  = ei + NE;
  const int* revp  = (const int*)d_in[2];
  const float* Wst = (const float*)d_in[3];
  const float* bst = (const float*)d_in[4];
  const float* Wts = (const float*)d_in[5];
  const float* bts = (const float*)d_in[6];
  const float* W1  = (const float*)d_in[7];
  const float* b1  = (const float*)d_in[8];
  const float* W2  = (const float*)d_in[9];
  const float* b2  = (const float*)d_in[10];
  const float* W3  = (const float*)d_in[11];
  const float* b3  = (const float*)d_in[12];
  float* out = (float*)d_out;

  char* ws = (char*)d_ws;
  size_t off = 0;
  auto alloc = [&](size_t bytes) -> void* {
    off = (off + 255) & ~size_t(255);
    void* p = ws + off;
    off += bytes;
    return p;
  };
  unsigned* cnt    = (unsigned*)alloc(sizeof(unsigned) * NN);
  unsigned* roff   = (unsigned*)alloc(sizeof(unsigned) * (NN + 1));
  unsigned* cursor = (unsigned*)alloc(sizeof(unsigned) * NN);
  unsigned* bsums  = (unsigned*)alloc(sizeof(unsigned) * 128);
  float*    Wcat   = (float*)alloc(sizeof(float) * 128 * 192);
  float4*   dinv4  = (float4*)alloc(sizeof(float4) * NN);
  uint4*    ecsr   = (uint4*)alloc(sizeof(uint4) * NE);
  // bufX: 51.2 MB (H' dup bf16 [N,256]; later T2' bf16 [N,128] and T3 fp32 [N,16])
  char*     bufX   = (char*)alloc((size_t)NN * 256 * 2);
  // bufY: 38.4 MB (h1 bf16 [N,192]; later h2 bf16 [N,128])
  char*     bufY   = (char*)alloc((size_t)NN * 192 * 2);
  (void)ws_size; (void)in_sizes; (void)n_in; (void)out_size;

  const int nbN = (NN + 255) / 256;
  const int nbE = (NE + 255) / 256;

  // CSR + degree + coefficient build
  hipLaunchKernelGGL(k_zero, dim3(nbN), dim3(256), 0, stream, cnt, NN);
  hipLaunchKernelGGL(k_deg, dim3(nbE), dim3(256), 0, stream, dstp, revp, cnt);
  hipLaunchKernelGGL(k_scan1, dim3(NB_SCAN), dim3(256), 0, stream, cnt, bsums);
  hipLaunchKernelGGL(k_scan2, dim3(1), dim3(128), 0, stream, bsums);
  hipLaunchKernelGGL(k_scan3, dim3(NB_SCAN), dim3(256), 0, stream, cnt, bsums, roff, cursor);
  hipLaunchKernelGGL(k_dinv, dim3(nbN), dim3(256), 0, stream, cnt, dinv4);
  hipLaunchKernelGGL(k_csr, dim3(nbE), dim3(256), 0, stream, srcp, dstp, revp, dinv4, cursor, ecsr);
  hipLaunchKernelGGL(k_packW, dim3((128 * 192 + 255) / 256), dim3(256), 0, stream,
                     Wst, Wts, W1, Wcat);

  // Layer 1: H' = x @ Wcat -> bufX (bf16 dup [N,256]); agg -> bufY (h1 bf16 [N,192])
  {
    int threads = (NN / 8) * (192 / 4);
    hipLaunchKernelGGL((k_gemm<128, 192, 0, 2>), dim3((threads + 255) / 256), dim3(256), 0, stream,
                       x, Wcat, bufX);
  }
  hipLaunchKernelGGL(k_agg1, dim3(NN / 4), dim3(256), 0, stream,
                     roff, ecsr, dinv4, (const unsigned*)bufX, bst, bts, b1, (unsigned*)bufY);

  // Layer 2: T2' = h1 @ W2 -> bufX (bf16 [N,128]); agg -> bufY (h2 bf16 [N,128])
  {
    int threads = (NN / 8) * (128 / 4);
    hipLaunchKernelGGL((k_gemm<192, 128, 1, 1>), dim3((threads + 255) / 256), dim3(256), 0, stream,
                       bufY, W2, bufX);
  }
  hipLaunchKernelGGL(k_agg2, dim3(NN / 4), dim3(256), 0, stream,
                     roff, ecsr, dinv4, (const unsigned*)bufX, b2, (unsigned*)bufY);

  // Layer 3: T3 = h2 @ W3 -> bufX fp32 [N,16]; agg + log_softmax -> out
  {
    int threads = (NN / 8) * (16 / 4);
    hipLaunchKernelGGL((k_gemm<128, 16, 1, 0>), dim3((threads + 255) / 256), dim3(256), 0, stream,
                       bufY, W3, bufX);
  }
  hipLaunchKernelGGL(k_agg3, dim3(NN / 16), dim3(256), 0, stream,
                     roff, ecsr, dinv4, (const float*)bufX, b3, out);
}

// Round 9
// 620.364 us; speedup vs baseline: 1.4840x; 1.2955x over previous
//
#include <hip/hip_runtime.h>
#include <math.h>

static constexpr int NN = 100000;   // nodes
static constexpr int NE = 1600000;  // edges
static constexpr int NB_SCAN = (NN + 1023) / 1024;  // 98 scan blocks

typedef __attribute__((ext_vector_type(8))) short bfvec8;  // 8 bf16 = 4 VGPRs
typedef __attribute__((ext_vector_type(4))) float fvec4;   // MFMA accumulator

// ---------------- bf16 helpers (fp32 <-> bf16 bit ops) ----------------
__device__ __forceinline__ float bflo(unsigned u) { return __uint_as_float(u << 16); }
__device__ __forceinline__ float bfhi(unsigned u) { return __uint_as_float(u & 0xFFFF0000u); }
__device__ __forceinline__ unsigned packbf2(float a, float b) {  // RTNE
  unsigned ua = __float_as_uint(a), ub = __float_as_uint(b);
  unsigned ra = (ua + 0x7fffu + ((ua >> 16) & 1u)) >> 16;
  unsigned rb = (ub + 0x7fffu + ((ub >> 16) & 1u)) >> 16;
  return ra | (rb << 16);
}
__device__ __forceinline__ unsigned short bf16r(float a) {  // RTNE single
  unsigned ua = __float_as_uint(a);
  return (unsigned short)((ua + 0x7fffu + ((ua >> 16) & 1u)) >> 16);
}

// ---------------- utility ----------------
__global__ __launch_bounds__(256) void k_zero(unsigned* __restrict__ p, int n) {
  int i = blockIdx.x * 256 + threadIdx.x;
  if (i < n) p[i] = 0u;
}

// Packed degree count: low16 = all-edge count, high16 = st (rev==0) count.
__global__ __launch_bounds__(256) void k_deg(const int* __restrict__ dst,
                                             const int* __restrict__ rev,
                                             unsigned* __restrict__ cnt) {
  int e = blockIdx.x * 256 + threadIdx.x;
  if (e >= NE) return;
  unsigned add = 1u + ((rev[e] == 0) ? 0x10000u : 0u);
  atomicAdd(&cnt[dst[e]], add);
}

// ---------------- scan of (cnt & 0xFFFF) ----------------
__global__ __launch_bounds__(256) void k_scan1(const unsigned* __restrict__ cnt,
                                               unsigned* __restrict__ bsums) {
  int g = blockIdx.x, t = threadIdx.x;
  int base = g * 1024 + t * 4;
  unsigned s = 0;
  #pragma unroll
  for (int j = 0; j < 4; ++j) {
    int i = base + j;
    if (i < NN) s += cnt[i] & 0xFFFFu;
  }
  __shared__ unsigned sm[256];
  sm[t] = s;
  __syncthreads();
  for (int o = 128; o > 0; o >>= 1) {
    if (t < o) sm[t] += sm[t + o];
    __syncthreads();
  }
  if (t == 0) bsums[g] = sm[0];
}

__global__ __launch_bounds__(128) void k_scan2(unsigned* __restrict__ bsums) {
  __shared__ unsigned sm[128];
  int t = threadIdx.x;
  unsigned v = (t < NB_SCAN) ? bsums[t] : 0u;
  sm[t] = v;
  __syncthreads();
  for (int o = 1; o < 128; o <<= 1) {
    unsigned u = (t >= o) ? sm[t - o] : 0u;
    __syncthreads();
    sm[t] += u;
    __syncthreads();
  }
  if (t < NB_SCAN) bsums[t] = sm[t] - v;  // exclusive
}

__global__ __launch_bounds__(256) void k_scan3(const unsigned* __restrict__ cnt,
                                               const unsigned* __restrict__ bsums,
                                               unsigned* __restrict__ roff,
                                               unsigned* __restrict__ cursor) {
  int g = blockIdx.x, t = threadIdx.x;
  int base = g * 1024 + t * 4;
  unsigned v[4];
  unsigned tsum = 0;
  #pragma unroll
  for (int j = 0; j < 4; ++j) {
    int i = base + j;
    v[j] = (i < NN) ? (cnt[i] & 0xFFFFu) : 0u;
    tsum += v[j];
  }
  __shared__ unsigned sm[256];
  sm[t] = tsum;
  __syncthreads();
  for (int o = 1; o < 256; o <<= 1) {
    unsigned u = (t >= o) ? sm[t - o] : 0u;
    __syncthreads();
    sm[t] += u;
    __syncthreads();
  }
  unsigned run = bsums[g] + sm[t] - tsum;  // exclusive prefix for this thread
  #pragma unroll
  for (int j = 0; j < 4; ++j) {
    int i = base + j;
    if (i < NN) {
      roff[i] = run;
      cursor[i] = run;
      run += v[j];
      if (i == NN - 1) roff[NN] = run;
    }
  }
}

// dinv4[n] = {rsqrt(deg_st), rsqrt(deg_ts), rsqrt(deg_all), 0}
__global__ __launch_bounds__(256) void k_dinv(const unsigned* __restrict__ cnt,
                                              float4* __restrict__ dinv4) {
  int n = blockIdx.x * 256 + threadIdx.x;
  if (n >= NN) return;
  unsigned c = cnt[n];
  float all = (float)(c & 0xFFFFu) + 1.0f;
  float st = (float)(c >> 16) + 1.0f;
  float ts = all - st + 1.0f;
  dinv4[n] = make_float4(rsqrtf(st), rsqrtf(ts), rsqrtf(all), 0.0f);
}

// CSR fill with precomputed per-edge coefficients:
// ecsr[p] = {src | rev<<31, bits(cB), bits(cAll), 0}
__global__ __launch_bounds__(256) void k_csr(const int* __restrict__ src,
                                             const int* __restrict__ dst,
                                             const int* __restrict__ rev,
                                             const float4* __restrict__ dinv4,
                                             unsigned* __restrict__ cursor,
                                             uint4* __restrict__ ecsr) {
  int e = blockIdx.x * 256 + threadIdx.x;
  if (e >= NE) return;
  int s = src[e], d = dst[e];
  int r = rev[e];
  float4 sv = dinv4[s];
  float4 dv = dinv4[d];
  float cB = r ? (sv.y * dv.y) : (sv.x * dv.x);
  float cA = sv.z * dv.z;
  unsigned p = atomicAdd(&cursor[d], 1u);
  ecsr[p] = make_uint4((unsigned)s | (r ? 0x80000000u : 0u),
                       __float_as_uint(cB), __float_as_uint(cA), 0u);
}

// Wcat logical layout [st(0-63) | all(64-127) | ts(128-191)]
__global__ __launch_bounds__(256) void k_packW(const float* __restrict__ Wst,
                                               const float* __restrict__ Wts,
                                               const float* __restrict__ W1,
                                               float* __restrict__ Wcat) {
  int i = blockIdx.x * 256 + threadIdx.x;
  if (i >= 128 * 192) return;
  int k = i / 192, c = i % 192;
  float v = (c < 64)  ? Wst[k * 64 + c]
          : (c < 128) ? W1[k * 64 + (c - 64)]
                      : Wts[k * 64 + (c - 128)];
  Wcat[i] = v;
}

// x fp32 -> bf16 row-major (one float4 -> uint2 per thread)
__global__ __launch_bounds__(256) void k_cvt(const float4* __restrict__ X,
                                             uint2* __restrict__ Xb, int n4) {
  int i = blockIdx.x * 256 + threadIdx.x;
  if (i >= n4) return;
  float4 v = X[i];
  Xb[i] = make_uint2(packbf2(v.x, v.y), packbf2(v.z, v.w));
}

// Pack fp32 W[K][NC] into MFMA B-fragment-major bf16:
// Wf[(c*(K/32)+t)*64 + lane] = { W[t*32+(lane>>4)*8+j][c*16+(lane&15)], j=0..7 }
template <int K, int NC>
__global__ __launch_bounds__(256) void k_packWf(const float* __restrict__ W,
                                                uint4* __restrict__ Wf) {
  constexpr int TOT = (NC / 16) * (K / 32) * 64;
  int i = blockIdx.x * 256 + threadIdx.x;
  if (i >= TOT) return;
  int lane = i & 63;
  int t = (i >> 6) % (K / 32);
  int c = i / ((K / 32) * 64);
  int col = c * 16 + (lane & 15);
  int k0 = t * 32 + (lane >> 4) * 8;
  float e[8];
  #pragma unroll
  for (int j = 0; j < 8; ++j) e[j] = W[(size_t)(k0 + j) * NC + col];
  Wf[i] = make_uint4(packbf2(e[0], e[1]), packbf2(e[2], e[3]),
                     packbf2(e[4], e[5]), packbf2(e[6], e[7]));
}

// ---------------- MFMA GEMM: O[N,NC] = A[N,K](bf16) @ Wf(bf16 frags) ----------------
// One wave per 16-row M-tile. A-frag: lane holds A[r0+(lane&15)][t*32+(lane>>4)*8+j].
// D mapping (m89-verified): col=lane&15, row=(lane>>4)*4+reg.
// OM: 0 = fp32 out [N,NC]; 1 = bf16 out [N,NC];
// 2 = bf16 dup layout [st|all|ts|alldup], row stride 256, tiles 4-7 dup'd to +128.
template <int K, int NC, int OM>
__global__ __launch_bounds__(256) void k_mgemm(const unsigned short* __restrict__ A,
                                               const bfvec8* __restrict__ Wf,
                                               void* __restrict__ Op) {
  constexpr int KS = K / 32, NCT = NC / 16;
  int wid = threadIdx.x >> 6, lane = threadIdx.x & 63;
  int rt = blockIdx.x * 4 + wid;
  if (rt >= NN / 16) return;
  int r0 = rt * 16;
  int row = lane & 15, hi = lane >> 4;
  bfvec8 af[KS];
  const unsigned short* Ab = A + (size_t)(r0 + row) * K + hi * 8;
  #pragma unroll
  for (int t = 0; t < KS; ++t) af[t] = *(const bfvec8*)(Ab + t * 32);
  #pragma unroll
  for (int c = 0; c < NCT; ++c) {
    fvec4 acc = {0.f, 0.f, 0.f, 0.f};
    #pragma unroll
    for (int t = 0; t < KS; ++t)
      acc = __builtin_amdgcn_mfma_f32_16x16x32_bf16(af[t], Wf[(c * KS + t) * 64 + lane],
                                                    acc, 0, 0, 0);
    if constexpr (OM == 0) {
      float* O = (float*)Op;
      #pragma unroll
      for (int r = 0; r < 4; ++r)
        O[(size_t)(r0 + hi * 4 + r) * NC + c * 16 + row] = acc[r];
    } else if constexpr (OM == 1) {
      unsigned short* O = (unsigned short*)Op;
      #pragma unroll
      for (int r = 0; r < 4; ++r)
        O[(size_t)(r0 + hi * 4 + r) * NC + c * 16 + row] = bf16r(acc[r]);
    } else {
      unsigned short* O = (unsigned short*)Op;
      #pragma unroll
      for (int r = 0; r < 4; ++r) {
        unsigned short v = bf16r(acc[r]);
        size_t base = (size_t)(r0 + hi * 4 + r) * 256 + c * 16 + row;
        O[base] = v;
        if (c >= 4 && c < 8) O[base + 128] = v;  // dup 'all' block to cols 192-255
      }
    }
  }
}

// ---------------- layer-1 aggregation ----------------
// H' rows: 256 bf16 = 128 uints: half0 = [st|all], half1 = [ts|all].
// Per edge ONE 256B load: lanes 0-31 -> B-block (st or ts), lanes 32-63 -> all.
// h1 out: bf16 [N,192] = 96 uints/row, layout [st|ts|all].
__global__ __launch_bounds__(256) void k_agg1(const unsigned* __restrict__ roff,
                                              const uint4* __restrict__ ecsr,
                                              const float4* __restrict__ dinv4,
                                              const unsigned* __restrict__ Hb,
                                              const float* __restrict__ bst,
                                              const float* __restrict__ bts,
                                              const float* __restrict__ b1,
                                              unsigned* __restrict__ h1) {
  int wid = threadIdx.x >> 6;
  int lane = threadIdx.x & 63;
  int d = blockIdx.x * 4 + wid;
  if (d >= NN) return;
  unsigned ro = roff[d], re = roff[d + 1];
  bool loB = lane < 32;
  float s0l = 0.f, s0h = 0.f, s1l = 0.f, s1h = 0.f, s2l = 0.f, s2h = 0.f;
  unsigned i = ro;
  for (; i + 2 <= re; i += 2) {
    uint4 e0 = ecsr[i];
    uint4 e1 = ecsr[i + 1];
    unsigned s0 = e0.x & 0x7FFFFFFFu, h0 = e0.x >> 31;
    unsigned s1 = e1.x & 0x7FFFFFFFu, h1b = e1.x >> 31;
    unsigned u0 = Hb[(size_t)s0 * 128 + h0 * 64 + lane];
    unsigned u1 = Hb[(size_t)s1 * 128 + h1b * 64 + lane];
    float c0 = loB ? __uint_as_float(e0.y) : __uint_as_float(e0.z);
    float c1 = loB ? __uint_as_float(e1.y) : __uint_as_float(e1.z);
    float a0l = c0 * bflo(u0), a0h = c0 * bfhi(u0);
    float a1l = c1 * bflo(u1), a1h = c1 * bfhi(u1);
    if (!loB)      { s2l += a0l; s2h += a0h; }
    else if (!h0)  { s0l += a0l; s0h += a0h; }
    else           { s1l += a0l; s1h += a0h; }
    if (!loB)      { s2l += a1l; s2h += a1h; }
    else if (!h1b) { s0l += a1l; s0h += a1h; }
    else           { s1l += a1l; s1h += a1h; }
  }
  for (; i < re; ++i) {
    uint4 e = ecsr[i];
    unsigned s = e.x & 0x7FFFFFFFu, h = e.x >> 31;
    unsigned u = Hb[(size_t)s * 128 + h * 64 + lane];
    float c = loB ? __uint_as_float(e.y) : __uint_as_float(e.z);
    float al = c * bflo(u), ah = c * bfhi(u);
    if (!loB)     { s2l += al; s2h += ah; }
    else if (!h)  { s0l += al; s0h += ah; }
    else          { s1l += al; s1h += ah; }
  }
  float4 dv = dinv4[d];
  unsigned u0 = Hb[(size_t)d * 128 + lane];        // half0: st | all
  unsigned u1 = Hb[(size_t)d * 128 + 64 + lane];   // half1: ts | all(dup)
  if (loB) {
    float rs = dv.x * dv.x, rt = dv.y * dv.y;
    s0l = fmaf(rs, bflo(u0), s0l); s0h = fmaf(rs, bfhi(u0), s0h);
    s1l = fmaf(rt, bflo(u1), s1l); s1h = fmaf(rt, bfhi(u1), s1h);
    float2 bs = ((const float2*)bst)[lane];
    float2 bt = ((const float2*)bts)[lane];
    s0l = fmaxf(s0l + bs.x, 0.f); s0h = fmaxf(s0h + bs.y, 0.f);
    s1l = fmaxf(s1l + bt.x, 0.f); s1h = fmaxf(s1h + bt.y, 0.f);
    h1[(size_t)d * 96 + lane] = packbf2(s0l, s0h);         // st cols 2l,2l+1
    h1[(size_t)d * 96 + 32 + lane] = packbf2(s1l, s1h);    // ts cols 64+2l
  } else {
    float ra = dv.z * dv.z;
    s2l = fmaf(ra, bflo(u0), s2l); s2h = fmaf(ra, bfhi(u0), s2h);
    float2 bb = ((const float2*)b1)[lane - 32];
    s2l = fmaxf(s2l + bb.x, 0.f); s2h = fmaxf(s2h + bb.y, 0.f);
    h1[(size_t)d * 96 + 64 + (lane - 32)] = packbf2(s2l, s2h);  // all cols 128+..
  }
}

// ---------------- layer-2 aggregation: T2' bf16 [N,128] = 64 uints/row ----------------
__global__ __launch_bounds__(256) void k_agg2(const unsigned* __restrict__ roff,
                                              const uint4* __restrict__ ecsr,
                                              const float4* __restrict__ dinv4,
                                              const unsigned* __restrict__ Tb,
                                              const float* __restrict__ b2,
                                              unsigned* __restrict__ h2) {
  int wid = threadIdx.x >> 6;
  int lane = threadIdx.x & 63;
  int d = blockIdx.x * 4 + wid;
  if (d >= NN) return;
  unsigned ro = roff[d], re = roff[d + 1];
  float sl = 0.f, sh = 0.f;
  unsigned i = ro;
  for (; i + 2 <= re; i += 2) {
    uint4 e0 = ecsr[i];
    uint4 e1 = ecsr[i + 1];
    unsigned s0 = e0.x & 0x7FFFFFFFu;
    unsigned s1 = e1.x & 0x7FFFFFFFu;
    unsigned u0 = Tb[(size_t)s0 * 64 + lane];
    unsigned u1 = Tb[(size_t)s1 * 64 + lane];
    float c0 = __uint_as_float(e0.z);
    float c1 = __uint_as_float(e1.z);
    sl = fmaf(c0, bflo(u0), sl); sh = fmaf(c0, bfhi(u0), sh);
    sl = fmaf(c1, bflo(u1), sl); sh = fmaf(c1, bfhi(u1), sh);
  }
  for (; i < re; ++i) {
    uint4 e = ecsr[i];
    unsigned s = e.x & 0x7FFFFFFFu;
    unsigned u = Tb[(size_t)s * 64 + lane];
    float c = __uint_as_float(e.z);
    sl = fmaf(c, bflo(u), sl); sh = fmaf(c, bfhi(u), sh);
  }
  float dz = dinv4[d].z;
  float ra = dz * dz;
  unsigned u = Tb[(size_t)d * 64 + lane];
  sl = fmaf(ra, bflo(u), sl); sh = fmaf(ra, bfhi(u), sh);
  float2 bb = ((const float2*)b2)[lane];
  sl += bb.x; sh += bb.y;
  h2[(size_t)d * 64 + lane] = packbf2(sl, sh);
}

// ---------------- layer-3 aggregation + log_softmax: T3 fp32 [N,16] ----------------
__global__ __launch_bounds__(256) void k_agg3(const unsigned* __restrict__ roff,
                                              const uint4* __restrict__ ecsr,
                                              const float4* __restrict__ dinv4,
                                              const float* __restrict__ T,
                                              const float* __restrict__ b3,
                                              float* __restrict__ out) {
  int g = threadIdx.x >> 4;
  int l = threadIdx.x & 15;
  int d = blockIdx.x * 16 + g;
  if (d >= NN) return;
  unsigned ro = roff[d], re = roff[d + 1];
  float a = 0.f;
  for (unsigned i = ro; i < re; ++i) {
    uint4 e = ecsr[i];
    unsigned s = e.x & 0x7FFFFFFFu;
    a = fmaf(__uint_as_float(e.z), T[(size_t)s * 16 + l], a);
  }
  float dz = dinv4[d].z;
  a = fmaf(dz * dz, T[(size_t)d * 16 + l], a) + b3[l];
  float m = a;
  #pragma unroll
  for (int o = 8; o > 0; o >>= 1) m = fmaxf(m, __shfl_xor(m, o, 16));
  float ex = expf(a - m);
  float sm = ex;
  #pragma unroll
  for (int o = 8; o > 0; o >>= 1) sm += __shfl_xor(sm, o, 16);
  out[(size_t)d * 16 + l] = a - m - logf(sm);
}

// ---------------- host-side launch ----------------
extern "C" void kernel_launch(void* const* d_in, const int* in_sizes, int n_in,
                              void* d_out, int out_size, void* d_ws, size_t ws_size,
                              hipStream_t stream) {
  const float* x   = (const float*)d_in[0];
  const int* ei    = (const int*)d_in[1];
  const int* srcp  = ei;
  const int* dstp  = ei + NE;
  const int* revp  = (const int*)d_in[2];
  const float* Wst = (const float*)d_in[3];
  const float* bst = (const float*)d_in[4];
  const float* Wts = (const float*)d_in[5];
  const float* bts = (const float*)d_in[6];
  const float* W1  = (const float*)d_in[7];
  const float* b1  = (const float*)d_in[8];
  const float* W2  = (const float*)d_in[9];
  const float* b2  = (const float*)d_in[10];
  const float* W3  = (const float*)d_in[11];
  const float* b3  = (const float*)d_in[12];
  float* out = (float*)d_out;

  char* ws = (char*)d_ws;
  size_t off = 0;
  auto alloc = [&](size_t bytes) -> void* {
    off = (off + 255) & ~size_t(255);
    void* p = ws + off;
    off += bytes;
    return p;
  };
  unsigned* cnt    = (unsigned*)alloc(sizeof(unsigned) * NN);
  unsigned* roff   = (unsigned*)alloc(sizeof(unsigned) * (NN + 1));
  unsigned* cursor = (unsigned*)alloc(sizeof(unsigned) * NN);
  unsigned* bsums  = (unsigned*)alloc(sizeof(unsigned) * 128);
  float*    Wcat   = (float*)alloc(sizeof(float) * 128 * 192);
  float4*   dinv4  = (float4*)alloc(sizeof(float4) * NN);
  uint4*    ecsr   = (uint4*)alloc(sizeof(uint4) * NE);
  // bufX: 51.2 MB (H' dup bf16 [N,256]; later T2' bf16 [N,128] and T3 fp32 [N,16])
  char*     bufX   = (char*)alloc((size_t)NN * 256 * 2);
  // bufY: 38.4 MB (h1 bf16 [N,192]; later h2 bf16 [N,128])
  char*     bufY   = (char*)alloc((size_t)NN * 192 * 2);
  // xb: 25.6 MB (x in bf16 row-major [N,128])
  unsigned short* xb = (unsigned short*)alloc((size_t)NN * 128 * 2);
  uint4*    Wf1    = (uint4*)alloc(sizeof(uint4) * 12 * 4 * 64);
  uint4*    Wf2    = (uint4*)alloc(sizeof(uint4) * 8 * 6 * 64);
  uint4*    Wf3    = (uint4*)alloc(sizeof(uint4) * 1 * 4 * 64);
  (void)ws_size; (void)in_sizes; (void)n_in; (void)out_size;

  const int nbN = (NN + 255) / 256;
  const int nbE = (NE + 255) / 256;
  const int nbM = (NN / 16 + 3) / 4;  // MFMA gemm blocks (4 waves x 16-row tiles)

  // CSR + degree + coefficient build
  hipLaunchKernelGGL(k_zero, dim3(nbN), dim3(256), 0, stream, cnt, NN);
  hipLaunchKernelGGL(k_deg, dim3(nbE), dim3(256), 0, stream, dstp, revp, cnt);
  hipLaunchKernelGGL(k_scan1, dim3(NB_SCAN), dim3(256), 0, stream, cnt, bsums);
  hipLaunchKernelGGL(k_scan2, dim3(1), dim3(128), 0, stream, bsums);
  hipLaunchKernelGGL(k_scan3, dim3(NB_SCAN), dim3(256), 0, stream, cnt, bsums, roff, cursor);
  hipLaunchKernelGGL(k_dinv, dim3(nbN), dim3(256), 0, stream, cnt, dinv4);
  hipLaunchKernelGGL(k_csr, dim3(nbE), dim3(256), 0, stream, srcp, dstp, revp, dinv4, cursor, ecsr);

  // Weight packing + x conversion
  hipLaunchKernelGGL(k_packW, dim3((128 * 192 + 255) / 256), dim3(256), 0, stream,
                     Wst, Wts, W1, Wcat);
  hipLaunchKernelGGL((k_packWf<128, 192>), dim3(12), dim3(256), 0, stream, Wcat, Wf1);
  hipLaunchKernelGGL((k_packWf<192, 128>), dim3(12), dim3(256), 0, stream, W2, Wf2);
  hipLaunchKernelGGL((k_packWf<128, 16>), dim3(1), dim3(256), 0, stream, W3, Wf3);
  hipLaunchKernelGGL(k_cvt, dim3(NN * 128 / 4 / 256), dim3(256), 0, stream,
                     (const float4*)x, (uint2*)xb, NN * 128 / 4);

  // Layer 1: H' = xb @ Wf1 -> bufX (bf16 dup [N,256]); agg -> bufY (h1 bf16 [N,192])
  hipLaunchKernelGGL((k_mgemm<128, 192, 2>), dim3(nbM), dim3(256), 0, stream,
                     xb, (const bfvec8*)Wf1, bufX);
  hipLaunchKernelGGL(k_agg1, dim3(NN / 4), dim3(256), 0, stream,
                     roff, ecsr, dinv4, (const unsigned*)bufX, bst, bts, b1, (unsigned*)bufY);

  // Layer 2: T2' = h1 @ Wf2 -> bufX (bf16 [N,128]); agg -> bufY (h2 bf16 [N,128])
  hipLaunchKernelGGL((k_mgemm<192, 128, 1>), dim3(nbM), dim3(256), 0, stream,
                     (const unsigned short*)bufY, (const bfvec8*)Wf2, bufX);
  hipLaunchKernelGGL(k_agg2, dim3(NN / 4), dim3(256), 0, stream,
                     roff, ecsr, dinv4, (const unsigned*)bufX, b2, (unsigned*)bufY);

  // Layer 3: T3 = h2 @ Wf3 -> bufX fp32 [N,16]; agg + log_softmax -> out
  hipLaunchKernelGGL((k_mgemm<128, 16, 0>), dim3(nbM), dim3(256), 0, stream,
                     (const unsigned short*)bufY, (const bfvec8*)Wf3, bufX);
  hipLaunchKernelGGL(k_agg3, dim3(NN / 16), dim3(256), 0, stream,
                     roff, ecsr, dinv4, (const float*)bufX, b3, out);
}

// Round 10
// 615.867 us; speedup vs baseline: 1.4949x; 1.0073x over previous
//
#include <hip/hip_runtime.h>
#include <math.h>

static constexpr int NN = 100000;   // nodes
static constexpr int NE = 1600000;  // edges
static constexpr int NB_SCAN = (NN + 1023) / 1024;  // 98 scan blocks

typedef __attribute__((ext_vector_type(8))) short bfvec8;  // 8 bf16 = 4 VGPRs
typedef __attribute__((ext_vector_type(4))) float fvec4;   // MFMA accumulator

// ---------------- bf16 helpers (fp32 <-> bf16 bit ops) ----------------
__device__ __forceinline__ float bflo(unsigned u) { return __uint_as_float(u << 16); }
__device__ __forceinline__ float bfhi(unsigned u) { return __uint_as_float(u & 0xFFFF0000u); }
__device__ __forceinline__ unsigned packbf2(float a, float b) {  // RTNE
  unsigned ua = __float_as_uint(a), ub = __float_as_uint(b);
  unsigned ra = (ua + 0x7fffu + ((ua >> 16) & 1u)) >> 16;
  unsigned rb = (ub + 0x7fffu + ((ub >> 16) & 1u)) >> 16;
  return ra | (rb << 16);
}
__device__ __forceinline__ unsigned short bf16r(float a) {  // RTNE single
  unsigned ua = __float_as_uint(a);
  return (unsigned short)((ua + 0x7fffu + ((ua >> 16) & 1u)) >> 16);
}

// ---------------- utility ----------------
__global__ __launch_bounds__(256) void k_zero(unsigned* __restrict__ p, int n) {
  int i = blockIdx.x * 256 + threadIdx.x;
  if (i < n) p[i] = 0u;
}

// Packed degree count: low16 = all-edge count, high16 = st (rev==0) count.
__global__ __launch_bounds__(256) void k_deg(const int* __restrict__ dst,
                                             const int* __restrict__ rev,
                                             unsigned* __restrict__ cnt) {
  int e = blockIdx.x * 256 + threadIdx.x;
  if (e >= NE) return;
  unsigned add = 1u + ((rev[e] == 0) ? 0x10000u : 0u);
  atomicAdd(&cnt[dst[e]], add);
}

// ---------------- scan of (cnt & 0xFFFF) ----------------
__global__ __launch_bounds__(256) void k_scan1(const unsigned* __restrict__ cnt,
                                               unsigned* __restrict__ bsums) {
  int g = blockIdx.x, t = threadIdx.x;
  int base = g * 1024 + t * 4;
  unsigned s = 0;
  #pragma unroll
  for (int j = 0; j < 4; ++j) {
    int i = base + j;
    if (i < NN) s += cnt[i] & 0xFFFFu;
  }
  __shared__ unsigned sm[256];
  sm[t] = s;
  __syncthreads();
  for (int o = 128; o > 0; o >>= 1) {
    if (t < o) sm[t] += sm[t + o];
    __syncthreads();
  }
  if (t == 0) bsums[g] = sm[0];
}

__global__ __launch_bounds__(128) void k_scan2(unsigned* __restrict__ bsums) {
  __shared__ unsigned sm[128];
  int t = threadIdx.x;
  unsigned v = (t < NB_SCAN) ? bsums[t] : 0u;
  sm[t] = v;
  __syncthreads();
  for (int o = 1; o < 128; o <<= 1) {
    unsigned u = (t >= o) ? sm[t - o] : 0u;
    __syncthreads();
    sm[t] += u;
    __syncthreads();
  }
  if (t < NB_SCAN) bsums[t] = sm[t] - v;  // exclusive
}

__global__ __launch_bounds__(256) void k_scan3(const unsigned* __restrict__ cnt,
                                               const unsigned* __restrict__ bsums,
                                               unsigned* __restrict__ roff,
                                               unsigned* __restrict__ cursor) {
  int g = blockIdx.x, t = threadIdx.x;
  int base = g * 1024 + t * 4;
  unsigned v[4];
  unsigned tsum = 0;
  #pragma unroll
  for (int j = 0; j < 4; ++j) {
    int i = base + j;
    v[j] = (i < NN) ? (cnt[i] & 0xFFFFu) : 0u;
    tsum += v[j];
  }
  __shared__ unsigned sm[256];
  sm[t] = tsum;
  __syncthreads();
  for (int o = 1; o < 256; o <<= 1) {
    unsigned u = (t >= o) ? sm[t - o] : 0u;
    __syncthreads();
    sm[t] += u;
    __syncthreads();
  }
  unsigned run = bsums[g] + sm[t] - tsum;  // exclusive prefix for this thread
  #pragma unroll
  for (int j = 0; j < 4; ++j) {
    int i = base + j;
    if (i < NN) {
      roff[i] = run;
      cursor[i] = run;
      run += v[j];
      if (i == NN - 1) roff[NN] = run;
    }
  }
}

// dinv4[n] = {rsqrt(deg_st), rsqrt(deg_ts), rsqrt(deg_all), 0}
__global__ __launch_bounds__(256) void k_dinv(const unsigned* __restrict__ cnt,
                                              float4* __restrict__ dinv4) {
  int n = blockIdx.x * 256 + threadIdx.x;
  if (n >= NN) return;
  unsigned c = cnt[n];
  float all = (float)(c & 0xFFFFu) + 1.0f;
  float st = (float)(c >> 16) + 1.0f;
  float ts = all - st + 1.0f;
  dinv4[n] = make_float4(rsqrtf(st), rsqrtf(ts), rsqrtf(all), 0.0f);
}

// CSR fill with precomputed per-edge coefficients:
// ecsr[p] = {src | rev<<31, bits(cB), bits(cAll), 0}
__global__ __launch_bounds__(256) void k_csr(const int* __restrict__ src,
                                             const int* __restrict__ dst,
                                             const int* __restrict__ rev,
                                             const float4* __restrict__ dinv4,
                                             unsigned* __restrict__ cursor,
                                             uint4* __restrict__ ecsr) {
  int e = blockIdx.x * 256 + threadIdx.x;
  if (e >= NE) return;
  int s = src[e], d = dst[e];
  int r = rev[e];
  float4 sv = dinv4[s];
  float4 dv = dinv4[d];
  float cB = r ? (sv.y * dv.y) : (sv.x * dv.x);
  float cA = sv.z * dv.z;
  unsigned p = atomicAdd(&cursor[d], 1u);
  ecsr[p] = make_uint4((unsigned)s | (r ? 0x80000000u : 0u),
                       __float_as_uint(cB), __float_as_uint(cA), 0u);
}

// x fp32 -> bf16 row-major (one float4 -> uint2 per thread)
__global__ __launch_bounds__(256) void k_cvt(const float4* __restrict__ X,
                                             uint2* __restrict__ Xb, int n4) {
  int i = blockIdx.x * 256 + threadIdx.x;
  if (i >= n4) return;
  float4 v = X[i];
  Xb[i] = make_uint2(packbf2(v.x, v.y), packbf2(v.z, v.w));
}

// Pack fp32 W[K][NC] into MFMA B-fragment-major bf16:
// Wf[(c*(K/32)+t)*64 + lane] = { W[t*32+(lane>>4)*8+j][c*16+(lane&15)], j=0..7 }
template <int K, int NC>
__global__ __launch_bounds__(256) void k_packWf(const float* __restrict__ W,
                                                uint4* __restrict__ Wf) {
  constexpr int TOT = (NC / 16) * (K / 32) * 64;
  int i = blockIdx.x * 256 + threadIdx.x;
  if (i >= TOT) return;
  int lane = i & 63;
  int t = (i >> 6) % (K / 32);
  int c = i / ((K / 32) * 64);
  int col = c * 16 + (lane & 15);
  int k0 = t * 32 + (lane >> 4) * 8;
  float e[8];
  #pragma unroll
  for (int j = 0; j < 8; ++j) e[j] = W[(size_t)(k0 + j) * NC + col];
  Wf[i] = make_uint4(packbf2(e[0], e[1]), packbf2(e[2], e[3]),
                     packbf2(e[4], e[5]), packbf2(e[6], e[7]));
}

// ---------------- layer-1 edge aggregation over x (bf16 [N,128]) ----------------
// agg(x@W) = agg(x)@W: aggregate x under 3 masks -> aST/aTS/aAL bf16 [N,128] each.
// One wave per node; lane holds cols {2*lane, 2*lane+1}. One 256B gather per edge.
// rev bit is wave-uniform per edge -> readfirstlane scalar branch (no cndmask bloat).
__global__ __launch_bounds__(256) void k_agg0(const unsigned* __restrict__ roff,
                                              const uint4* __restrict__ ecsr,
                                              const float4* __restrict__ dinv4,
                                              const unsigned* __restrict__ Xb,
                                              unsigned* __restrict__ aST,
                                              unsigned* __restrict__ aTS,
                                              unsigned* __restrict__ aAL) {
  int wid = threadIdx.x >> 6;
  int lane = threadIdx.x & 63;
  int d = blockIdx.x * 4 + wid;
  if (d >= NN) return;
  unsigned ro = roff[d], re = roff[d + 1];
  float s0l = 0.f, s0h = 0.f, s1l = 0.f, s1h = 0.f, s2l = 0.f, s2h = 0.f;
  unsigned i = ro;
  for (; i + 2 <= re; i += 2) {
    uint4 e0 = ecsr[i];
    uint4 e1 = ecsr[i + 1];
    unsigned u0 = Xb[(size_t)(e0.x & 0x7FFFFFFFu) * 64 + lane];
    unsigned u1 = Xb[(size_t)(e1.x & 0x7FFFFFFFu) * 64 + lane];
    float x0l = bflo(u0), x0h = bfhi(u0);
    float x1l = bflo(u1), x1h = bfhi(u1);
    float cA0 = __uint_as_float(e0.z), cB0 = __uint_as_float(e0.y);
    float cA1 = __uint_as_float(e1.z), cB1 = __uint_as_float(e1.y);
    s2l = fmaf(cA0, x0l, s2l); s2h = fmaf(cA0, x0h, s2h);
    s2l = fmaf(cA1, x1l, s2l); s2h = fmaf(cA1, x1h, s2h);
    if (!(__builtin_amdgcn_readfirstlane(e0.x) & 0x80000000u)) {
      s0l = fmaf(cB0, x0l, s0l); s0h = fmaf(cB0, x0h, s0h);
    } else {
      s1l = fmaf(cB0, x0l, s1l); s1h = fmaf(cB0, x0h, s1h);
    }
    if (!(__builtin_amdgcn_readfirstlane(e1.x) & 0x80000000u)) {
      s0l = fmaf(cB1, x1l, s0l); s0h = fmaf(cB1, x1h, s0h);
    } else {
      s1l = fmaf(cB1, x1l, s1l); s1h = fmaf(cB1, x1h, s1h);
    }
  }
  for (; i < re; ++i) {
    uint4 e = ecsr[i];
    unsigned u = Xb[(size_t)(e.x & 0x7FFFFFFFu) * 64 + lane];
    float xl = bflo(u), xh = bfhi(u);
    float cA = __uint_as_float(e.z), cB = __uint_as_float(e.y);
    s2l = fmaf(cA, xl, s2l); s2h = fmaf(cA, xh, s2h);
    if (!(__builtin_amdgcn_readfirstlane(e.x) & 0x80000000u)) {
      s0l = fmaf(cB, xl, s0l); s0h = fmaf(cB, xh, s0h);
    } else {
      s1l = fmaf(cB, xl, s1l); s1h = fmaf(cB, xh, s1h);
    }
  }
  // self-loop terms: dinv^2 * x_d per mask
  float4 dv = dinv4[d];
  unsigned u = Xb[(size_t)d * 64 + lane];
  float xl = bflo(u), xh = bfhi(u);
  float rs = dv.x * dv.x, rt = dv.y * dv.y, ra = dv.z * dv.z;
  s0l = fmaf(rs, xl, s0l); s0h = fmaf(rs, xh, s0h);
  s1l = fmaf(rt, xl, s1l); s1h = fmaf(rt, xh, s1h);
  s2l = fmaf(ra, xl, s2l); s2h = fmaf(ra, xh, s2h);
  aST[(size_t)d * 64 + lane] = packbf2(s0l, s0h);
  aTS[(size_t)d * 64 + lane] = packbf2(s1l, s1h);
  aAL[(size_t)d * 64 + lane] = packbf2(s2l, s2h);
}

// ---------------- fused layer-1 GEMM: h1 = relu([aST@Wst | aTS@Wts | aAL@W1] + b) ----------------
// h1 bf16 [N,192], layout [st|ts|all] (matches W2 row order).
__global__ __launch_bounds__(256) void k_mgemm1f(const unsigned short* __restrict__ A0,
                                                 const unsigned short* __restrict__ A1,
                                                 const unsigned short* __restrict__ A2,
                                                 const bfvec8* __restrict__ W0,
                                                 const bfvec8* __restrict__ W1f,
                                                 const bfvec8* __restrict__ W2f,
                                                 const float* __restrict__ b0,
                                                 const float* __restrict__ b1p,
                                                 const float* __restrict__ b2p,
                                                 unsigned short* __restrict__ O) {
  int wid = threadIdx.x >> 6, lane = threadIdx.x & 63;
  int rt = blockIdx.x * 4 + wid;
  if (rt >= NN / 16) return;
  int r0 = rt * 16, row = lane & 15, hi = lane >> 4;
  #pragma unroll
  for (int b = 0; b < 3; ++b) {
    const unsigned short* Ab = (b == 0 ? A0 : b == 1 ? A1 : A2) + (size_t)(r0 + row) * 128 + hi * 8;
    const bfvec8* Wb = (b == 0 ? W0 : b == 1 ? W1f : W2f);
    const float* bb = (b == 0 ? b0 : b == 1 ? b1p : b2p);
    bfvec8 af[4];
    #pragma unroll
    for (int t = 0; t < 4; ++t) af[t] = *(const bfvec8*)(Ab + t * 32);
    #pragma unroll
    for (int ct = 0; ct < 4; ++ct) {
      fvec4 acc = {0.f, 0.f, 0.f, 0.f};
      #pragma unroll
      for (int t = 0; t < 4; ++t)
        acc = __builtin_amdgcn_mfma_f32_16x16x32_bf16(af[t], Wb[(ct * 4 + t) * 64 + lane],
                                                      acc, 0, 0, 0);
      float bv = bb[ct * 16 + row];
      #pragma unroll
      for (int r = 0; r < 4; ++r)
        O[(size_t)(r0 + hi * 4 + r) * 192 + b * 64 + ct * 16 + row] =
            bf16r(fmaxf(acc[r] + bv, 0.f));
    }
  }
}

// ---------------- MFMA GEMM: O[N,NC] = A[N,K](bf16) @ Wf(bf16 frags) ----------------
// One wave per 16-row M-tile. A-frag: lane holds A[r0+(lane&15)][t*32+(lane>>4)*8+j].
// D mapping (m89-verified): col=lane&15, row=(lane>>4)*4+reg.
// OM: 0 = fp32 out [N,NC]; 1 = bf16 out [N,NC].
template <int K, int NC, int OM>
__global__ __launch_bounds__(256) void k_mgemm(const unsigned short* __restrict__ A,
                                               const bfvec8* __restrict__ Wf,
                                               void* __restrict__ Op) {
  constexpr int KS = K / 32, NCT = NC / 16;
  int wid = threadIdx.x >> 6, lane = threadIdx.x & 63;
  int rt = blockIdx.x * 4 + wid;
  if (rt >= NN / 16) return;
  int r0 = rt * 16;
  int row = lane & 15, hi = lane >> 4;
  bfvec8 af[KS];
  const unsigned short* Ab = A + (size_t)(r0 + row) * K + hi * 8;
  #pragma unroll
  for (int t = 0; t < KS; ++t) af[t] = *(const bfvec8*)(Ab + t * 32);
  #pragma unroll
  for (int c = 0; c < NCT; ++c) {
    fvec4 acc = {0.f, 0.f, 0.f, 0.f};
    #pragma unroll
    for (int t = 0; t < KS; ++t)
      acc = __builtin_amdgcn_mfma_f32_16x16x32_bf16(af[t], Wf[(c * KS + t) * 64 + lane],
                                                    acc, 0, 0, 0);
    if constexpr (OM == 0) {
      float* O = (float*)Op;
      #pragma unroll
      for (int r = 0; r < 4; ++r)
        O[(size_t)(r0 + hi * 4 + r) * NC + c * 16 + row] = acc[r];
    } else {
      unsigned short* O = (unsigned short*)Op;
      #pragma unroll
      for (int r = 0; r < 4; ++r)
        O[(size_t)(r0 + hi * 4 + r) * NC + c * 16 + row] = bf16r(acc[r]);
    }
  }
}

// ---------------- layer-2 aggregation: T2' bf16 [N,128] = 64 uints/row ----------------
__global__ __launch_bounds__(256) void k_agg2(const unsigned* __restrict__ roff,
                                              const uint4* __restrict__ ecsr,
                                              const float4* __restrict__ dinv4,
                                              const unsigned* __restrict__ Tb,
                                              const float* __restrict__ b2,
                                              unsigned* __restrict__ h2) {
  int wid = threadIdx.x >> 6;
  int lane = threadIdx.x & 63;
  int d = blockIdx.x * 4 + wid;
  if (d >= NN) return;
  unsigned ro = roff[d], re = roff[d + 1];
  float sl = 0.f, sh = 0.f;
  unsigned i = ro;
  for (; i + 2 <= re; i += 2) {
    uint4 e0 = ecsr[i];
    uint4 e1 = ecsr[i + 1];
    unsigned s0 = e0.x & 0x7FFFFFFFu;
    unsigned s1 = e1.x & 0x7FFFFFFFu;
    unsigned u0 = Tb[(size_t)s0 * 64 + lane];
    unsigned u1 = Tb[(size_t)s1 * 64 + lane];
    float c0 = __uint_as_float(e0.z);
    float c1 = __uint_as_float(e1.z);
    sl = fmaf(c0, bflo(u0), sl); sh = fmaf(c0, bfhi(u0), sh);
    sl = fmaf(c1, bflo(u1), sl); sh = fmaf(c1, bfhi(u1), sh);
  }
  for (; i < re; ++i) {
    uint4 e = ecsr[i];
    unsigned s = e.x & 0x7FFFFFFFu;
    unsigned u = Tb[(size_t)s * 64 + lane];
    float c = __uint_as_float(e.z);
    sl = fmaf(c, bflo(u), sl); sh = fmaf(c, bfhi(u), sh);
  }
  float dz = dinv4[d].z;
  float ra = dz * dz;
  unsigned u = Tb[(size_t)d * 64 + lane];
  sl = fmaf(ra, bflo(u), sl); sh = fmaf(ra, bfhi(u), sh);
  float2 bb = ((const float2*)b2)[lane];
  sl += bb.x; sh += bb.y;
  h2[(size_t)d * 64 + lane] = packbf2(sl, sh);
}

// ---------------- layer-3 aggregation + log_softmax: T3 fp32 [N,16] ----------------
__global__ __launch_bounds__(256) void k_agg3(const unsigned* __restrict__ roff,
                                              const uint4* __restrict__ ecsr,
                                              const float4* __restrict__ dinv4,
                                              const float* __restrict__ T,
                                              const float* __restrict__ b3,
                                              float* __restrict__ out) {
  int g = threadIdx.x >> 4;
  int l = threadIdx.x & 15;
  int d = blockIdx.x * 16 + g;
  if (d >= NN) return;
  unsigned ro = roff[d], re = roff[d + 1];
  float a = 0.f;
  for (unsigned i = ro; i < re; ++i) {
    uint4 e = ecsr[i];
    unsigned s = e.x & 0x7FFFFFFFu;
    a = fmaf(__uint_as_float(e.z), T[(size_t)s * 16 + l], a);
  }
  float dz = dinv4[d].z;
  a = fmaf(dz * dz, T[(size_t)d * 16 + l], a) + b3[l];
  float m = a;
  #pragma unroll
  for (int o = 8; o > 0; o >>= 1) m = fmaxf(m, __shfl_xor(m, o, 16));
  float ex = expf(a - m);
  float sm = ex;
  #pragma unroll
  for (int o = 8; o > 0; o >>= 1) sm += __shfl_xor(sm, o, 16);
  out[(size_t)d * 16 + l] = a - m - logf(sm);
}

// ---------------- host-side launch ----------------
extern "C" void kernel_launch(void* const* d_in, const int* in_sizes, int n_in,
                              void* d_out, int out_size, void* d_ws, size_t ws_size,
                              hipStream_t stream) {
  const float* x   = (const float*)d_in[0];
  const int* ei    = (const int*)d_in[1];
  const int* srcp  = ei;
  const int* dstp  = ei + NE;
  const int* revp  = (const int*)d_in[2];
  const float* Wst = (const float*)d_in[3];
  const float* bst = (const float*)d_in[4];
  const float* Wts = (const float*)d_in[5];
  const float* bts = (const float*)d_in[6];
  const float* W1  = (const float*)d_in[7];
  const float* b1  = (const float*)d_in[8];
  const float* W2  = (const float*)d_in[9];
  const float* b2  = (const float*)d_in[10];
  const float* W3  = (const float*)d_in[11];
  const float* b3  = (const float*)d_in[12];
  float* out = (float*)d_out;

  char* ws = (char*)d_ws;
  size_t off = 0;
  auto alloc = [&](size_t bytes) -> void* {
    off = (off + 255) & ~size_t(255);
    void* p = ws + off;
    off += bytes;
    return p;
  };
  unsigned* cnt    = (unsigned*)alloc(sizeof(unsigned) * NN);
  unsigned* roff   = (unsigned*)alloc(sizeof(unsigned) * (NN + 1));
  unsigned* cursor = (unsigned*)alloc(sizeof(unsigned) * NN);
  unsigned* bsums  = (unsigned*)alloc(sizeof(unsigned) * 128);
  float4*   dinv4  = (float4*)alloc(sizeof(float4) * NN);
  uint4*    ecsr   = (uint4*)alloc(sizeof(uint4) * NE);
  // bufX: 25.6 MB (aggST bf16 [N,128]; later T2' bf16 [N,128] and T3 fp32 [N,16])
  char*     bufX   = (char*)alloc((size_t)NN * 128 * 2);
  unsigned* aggTS  = (unsigned*)alloc(sizeof(unsigned) * (size_t)NN * 64);  // 25.6 MB
  unsigned* aggAL  = (unsigned*)alloc(sizeof(unsigned) * (size_t)NN * 64);  // 25.6 MB
  // bufY: 38.4 MB (h1 bf16 [N,192]; later h2 bf16 [N,128])
  char*     bufY   = (char*)alloc((size_t)NN * 192 * 2);
  // xb: 25.6 MB (x in bf16 row-major [N,128])
  unsigned short* xb = (unsigned short*)alloc((size_t)NN * 128 * 2);
  uint4*    WfS    = (uint4*)alloc(sizeof(uint4) * 4 * 4 * 64);
  uint4*    WfT    = (uint4*)alloc(sizeof(uint4) * 4 * 4 * 64);
  uint4*    Wf1    = (uint4*)alloc(sizeof(uint4) * 4 * 4 * 64);
  uint4*    Wf2    = (uint4*)alloc(sizeof(uint4) * 8 * 6 * 64);
  uint4*    Wf3    = (uint4*)alloc(sizeof(uint4) * 1 * 4 * 64);
  (void)ws_size; (void)in_sizes; (void)n_in; (void)out_size;

  const int nbN = (NN + 255) / 256;
  const int nbE = (NE + 255) / 256;
  const int nbM = (NN / 16 + 3) / 4;  // MFMA gemm blocks (4 waves x 16-row tiles)

  // CSR + degree + coefficient build
  hipLaunchKernelGGL(k_zero, dim3(nbN), dim3(256), 0, stream, cnt, NN);
  hipLaunchKernelGGL(k_deg, dim3(nbE), dim3(256), 0, stream, dstp, revp, cnt);
  hipLaunchKernelGGL(k_scan1, dim3(NB_SCAN), dim3(256), 0, stream, cnt, bsums);
  hipLaunchKernelGGL(k_scan2, dim3(1), dim3(128), 0, stream, bsums);
  hipLaunchKernelGGL(k_scan3, dim3(NB_SCAN), dim3(256), 0, stream, cnt, bsums, roff, cursor);
  hipLaunchKernelGGL(k_dinv, dim3(nbN), dim3(256), 0, stream, cnt, dinv4);
  hipLaunchKernelGGL(k_csr, dim3(nbE), dim3(256), 0, stream, srcp, dstp, revp, dinv4, cursor, ecsr);

  // Weight packing + x conversion
  hipLaunchKernelGGL((k_packWf<128, 64>), dim3(4), dim3(256), 0, stream, Wst, WfS);
  hipLaunchKernelGGL((k_packWf<128, 64>), dim3(4), dim3(256), 0, stream, Wts, WfT);
  hipLaunchKernelGGL((k_packWf<128, 64>), dim3(4), dim3(256), 0, stream, W1, Wf1);
  hipLaunchKernelGGL((k_packWf<192, 128>), dim3(12), dim3(256), 0, stream, W2, Wf2);
  hipLaunchKernelGGL((k_packWf<128, 16>), dim3(1), dim3(256), 0, stream, W3, Wf3);
  hipLaunchKernelGGL(k_cvt, dim3(NN * 128 / 4 / 256), dim3(256), 0, stream,
                     (const float4*)x, (uint2*)xb, NN * 128 / 4);

  // Layer 1: aggregate x under 3 masks, then fused block GEMM + bias + relu
  hipLaunchKernelGGL(k_agg0, dim3(NN / 4), dim3(256), 0, stream,
                     roff, ecsr, dinv4, (const unsigned*)xb,
                     (unsigned*)bufX, aggTS, aggAL);
  hipLaunchKernelGGL(k_mgemm1f, dim3(nbM), dim3(256), 0, stream,
                     (const unsigned short*)bufX, (const unsigned short*)aggTS,
                     (const unsigned short*)aggAL,
                     (const bfvec8*)WfS, (const bfvec8*)WfT, (const bfvec8*)Wf1,
                     bst, bts, b1, (unsigned short*)bufY);

  // Layer 2: T2' = h1 @ Wf2 -> bufX (bf16 [N,128]); agg -> bufY (h2 bf16 [N,128])
  hipLaunchKernelGGL((k_mgemm<192, 128, 1>), dim3(nbM), dim3(256), 0, stream,
                     (const unsigned short*)bufY, (const bfvec8*)Wf2, bufX);
  hipLaunchKernelGGL(k_agg2, dim3(NN / 4), dim3(256), 0, stream,
                     roff, ecsr, dinv4, (const unsigned*)bufX, b2, (unsigned*)bufY);

  // Layer 3: T3 = h2 @ Wf3 -> bufX fp32 [N,16]; agg + log_softmax -> out
  hipLaunchKernelGGL((k_mgemm<128, 16, 0>), dim3(nbM), dim3(256), 0, stream,
                     (const unsigned short*)bufY, (const bfvec8*)Wf3, bufX);
  hipLaunchKernelGGL(k_agg3, dim3(NN / 16), dim3(256), 0, stream,
                     roff, ecsr, dinv4, (const float*)bufX, b3, out);
}

// Round 12
// 554.948 us; speedup vs baseline: 1.6590x; 1.1098x over previous
//
#include <hip/hip_runtime.h>
#include <hip/hip_fp16.h>
#include <math.h>

static constexpr int NN = 100000;   // nodes
static constexpr int NE = 1600000;  // edges
static constexpr int NB_SCAN = (NN + 1023) / 1024;  // 98 scan blocks

typedef __attribute__((ext_vector_type(8))) short bfvec8;  // 8 bf16 = 4 VGPRs
typedef __attribute__((ext_vector_type(4))) float fvec4;   // MFMA accumulator

// ---------------- bf16 helpers (fp32 <-> bf16 bit ops) ----------------
__device__ __forceinline__ float bflo(unsigned u) { return __uint_as_float(u << 16); }
__device__ __forceinline__ float bfhi(unsigned u) { return __uint_as_float(u & 0xFFFF0000u); }
__device__ __forceinline__ unsigned packbf2(float a, float b) {  // RTNE
  unsigned ua = __float_as_uint(a), ub = __float_as_uint(b);
  unsigned ra = (ua + 0x7fffu + ((ua >> 16) & 1u)) >> 16;
  unsigned rb = (ub + 0x7fffu + ((ub >> 16) & 1u)) >> 16;
  return ra | (rb << 16);
}
__device__ __forceinline__ unsigned short bf16r(float a) {  // RTNE single
  unsigned ua = __float_as_uint(a);
  return (unsigned short)((ua + 0x7fffu + ((ua >> 16) & 1u)) >> 16);
}
__device__ __forceinline__ float2 coefs(unsigned y) {  // {cB, cA} from packed half2
  return __half22float2(*(const __half2*)&y);
}

// ---------------- utility ----------------
__global__ __launch_bounds__(256) void k_zero(unsigned* __restrict__ p, int n) {
  int i = blockIdx.x * 256 + threadIdx.x;
  if (i < n) p[i] = 0u;
}

// Packed degree count: low16 = all-edge count, high16 = st (rev==0) count.
__global__ __launch_bounds__(256) void k_deg(const int* __restrict__ dst,
                                             const int* __restrict__ rev,
                                             unsigned* __restrict__ cnt) {
  int e = blockIdx.x * 256 + threadIdx.x;
  if (e >= NE) return;
  unsigned add = 1u + ((rev[e] == 0) ? 0x10000u : 0u);
  atomicAdd(&cnt[dst[e]], add);
}

// ---------------- scan of (cnt & 0xFFFF) ----------------
__global__ __launch_bounds__(256) void k_scan1(const unsigned* __restrict__ cnt,
                                               unsigned* __restrict__ bsums) {
  int g = blockIdx.x, t = threadIdx.x;
  int base = g * 1024 + t * 4;
  unsigned s = 0;
  #pragma unroll
  for (int j = 0; j < 4; ++j) {
    int i = base + j;
    if (i < NN) s += cnt[i] & 0xFFFFu;
  }
  __shared__ unsigned sm[256];
  sm[t] = s;
  __syncthreads();
  for (int o = 128; o > 0; o >>= 1) {
    if (t < o) sm[t] += sm[t + o];
    __syncthreads();
  }
  if (t == 0) bsums[g] = sm[0];
}

__global__ __launch_bounds__(128) void k_scan2(unsigned* __restrict__ bsums) {
  __shared__ unsigned sm[128];
  int t = threadIdx.x;
  unsigned v = (t < NB_SCAN) ? bsums[t] : 0u;
  sm[t] = v;
  __syncthreads();
  for (int o = 1; o < 128; o <<= 1) {
    unsigned u = (t >= o) ? sm[t - o] : 0u;
    __syncthreads();
    sm[t] += u;
    __syncthreads();
  }
  if (t < NB_SCAN) bsums[t] = sm[t] - v;  // exclusive
}

__global__ __launch_bounds__(256) void k_scan3(const unsigned* __restrict__ cnt,
                                               const unsigned* __restrict__ bsums,
                                               unsigned* __restrict__ roff,
                                               unsigned* __restrict__ cursor) {
  int g = blockIdx.x, t = threadIdx.x;
  int base = g * 1024 + t * 4;
  unsigned v[4];
  unsigned tsum = 0;
  #pragma unroll
  for (int j = 0; j < 4; ++j) {
    int i = base + j;
    v[j] = (i < NN) ? (cnt[i] & 0xFFFFu) : 0u;
    tsum += v[j];
  }
  __shared__ unsigned sm[256];
  sm[t] = tsum;
  __syncthreads();
  for (int o = 1; o < 256; o <<= 1) {
    unsigned u = (t >= o) ? sm[t - o] : 0u;
    __syncthreads();
    sm[t] += u;
    __syncthreads();
  }
  unsigned run = bsums[g] + sm[t] - tsum;  // exclusive prefix for this thread
  #pragma unroll
  for (int j = 0; j < 4; ++j) {
    int i = base + j;
    if (i < NN) {
      roff[i] = run;
      cursor[i] = run;
      run += v[j];
      if (i == NN - 1) roff[NN] = run;
    }
  }
}

// dinv4[n] = {rsqrt(deg_st), rsqrt(deg_ts), rsqrt(deg_all), 0}
__global__ __launch_bounds__(256) void k_dinv(const unsigned* __restrict__ cnt,
                                              float4* __restrict__ dinv4) {
  int n = blockIdx.x * 256 + threadIdx.x;
  if (n >= NN) return;
  unsigned c = cnt[n];
  float all = (float)(c & 0xFFFFu) + 1.0f;
  float st = (float)(c >> 16) + 1.0f;
  float ts = all - st + 1.0f;
  dinv4[n] = make_float4(rsqrtf(st), rsqrtf(ts), rsqrtf(all), 0.0f);
}

// CSR fill with precomputed per-edge coefficients (8B records):
// ecsr[p] = {src | rev<<31, half2(cB, cA)}
__global__ __launch_bounds__(256) void k_csr(const int* __restrict__ src,
                                             const int* __restrict__ dst,
                                             const int* __restrict__ rev,
                                             const float4* __restrict__ dinv4,
                                             unsigned* __restrict__ cursor,
                                             uint2* __restrict__ ecsr) {
  int e = blockIdx.x * 256 + threadIdx.x;
  if (e >= NE) return;
  int s = src[e], d = dst[e];
  int r = rev[e];
  float4 sv = dinv4[s];
  float4 dv = dinv4[d];
  float cB = r ? (sv.y * dv.y) : (sv.x * dv.x);
  float cA = sv.z * dv.z;
  __half2 h = __floats2half2_rn(cB, cA);
  unsigned p = atomicAdd(&cursor[d], 1u);
  ecsr[p] = make_uint2((unsigned)s | (r ? 0x80000000u : 0u), *(const unsigned*)&h);
}

// x fp32 -> bf16 row-major (one float4 -> uint2 per thread)
__global__ __launch_bounds__(256) void k_cvt(const float4* __restrict__ X,
                                             uint2* __restrict__ Xb, int n4) {
  int i = blockIdx.x * 256 + threadIdx.x;
  if (i >= n4) return;
  float4 v = X[i];
  Xb[i] = make_uint2(packbf2(v.x, v.y), packbf2(v.z, v.w));
}

// Pack fp32 W[K][NC] into MFMA B-fragment-major bf16:
// Wf[(c*(K/32)+t)*64 + lane] = { W[t*32+(lane>>4)*8+j][c*16+(lane&15)], j=0..7 }
template <int K, int NC>
__global__ __launch_bounds__(256) void k_packWf(const float* __restrict__ W,
                                                uint4* __restrict__ Wf) {
  constexpr int TOT = (NC / 16) * (K / 32) * 64;
  int i = blockIdx.x * 256 + threadIdx.x;
  if (i >= TOT) return;
  int lane = i & 63;
  int t = (i >> 6) % (K / 32);
  int c = i / ((K / 32) * 64);
  int col = c * 16 + (lane & 15);
  int k0 = t * 32 + (lane >> 4) * 8;
  float e[8];
  #pragma unroll
  for (int j = 0; j < 8; ++j) e[j] = W[(size_t)(k0 + j) * NC + col];
  Wf[i] = make_uint4(packbf2(e[0], e[1]), packbf2(e[2], e[3]),
                     packbf2(e[4], e[5]), packbf2(e[6], e[7]));
}

// ---------------- layer-1 edge aggregation over x (bf16 [N,128]) ----------------
// One wave per node; lane holds cols {2*lane, 2*lane+1}.
// Unroll x4: 4 independent ecsr loads then 4 independent 256B gathers per chain-step.
// Accumulator select via zeroed coefficient (cndmask), no branches in the hot loop.
__global__ __launch_bounds__(256) void k_agg0(const unsigned* __restrict__ roff,
                                              const uint2* __restrict__ E,
                                              const float4* __restrict__ dinv4,
                                              const unsigned* __restrict__ Xb,
                                              unsigned* __restrict__ aST,
                                              unsigned* __restrict__ aTS,
                                              unsigned* __restrict__ aAL) {
  int wid = threadIdx.x >> 6;
  int lane = threadIdx.x & 63;
  int d = blockIdx.x * 4 + wid;
  if (d >= NN) return;
  unsigned ro = roff[d], re = roff[d + 1];
  float s0l = 0.f, s0h = 0.f, s1l = 0.f, s1h = 0.f, s2l = 0.f, s2h = 0.f;
  unsigned i = ro;
#define A0_EDGE(e, u)                                              \
  {                                                                \
    float2 c = coefs(e.y);                                         \
    bool ts = (e.x & 0x80000000u) != 0;                            \
    float cB0 = ts ? 0.f : c.x;                                    \
    float cB1 = ts ? c.x : 0.f;                                    \
    float xl = bflo(u), xh = bfhi(u);                              \
    s2l = fmaf(c.y, xl, s2l); s2h = fmaf(c.y, xh, s2h);            \
    s0l = fmaf(cB0, xl, s0l); s0h = fmaf(cB0, xh, s0h);            \
    s1l = fmaf(cB1, xl, s1l); s1h = fmaf(cB1, xh, s1h);            \
  }
  for (; i + 4 <= re; i += 4) {
    uint2 e0 = E[i], e1 = E[i + 1], e2 = E[i + 2], e3 = E[i + 3];
    unsigned u0 = Xb[(size_t)(e0.x & 0x7FFFFFFFu) * 64 + lane];
    unsigned u1 = Xb[(size_t)(e1.x & 0x7FFFFFFFu) * 64 + lane];
    unsigned u2 = Xb[(size_t)(e2.x & 0x7FFFFFFFu) * 64 + lane];
    unsigned u3 = Xb[(size_t)(e3.x & 0x7FFFFFFFu) * 64 + lane];
    A0_EDGE(e0, u0) A0_EDGE(e1, u1) A0_EDGE(e2, u2) A0_EDGE(e3, u3)
  }
  for (; i < re; ++i) {
    uint2 e = E[i];
    unsigned u = Xb[(size_t)(e.x & 0x7FFFFFFFu) * 64 + lane];
    A0_EDGE(e, u)
  }
#undef A0_EDGE
  // self-loop terms: dinv^2 * x_d per mask
  float4 dv = dinv4[d];
  unsigned u = Xb[(size_t)d * 64 + lane];
  float xl = bflo(u), xh = bfhi(u);
  float rs = dv.x * dv.x, rt = dv.y * dv.y, ra = dv.z * dv.z;
  s0l = fmaf(rs, xl, s0l); s0h = fmaf(rs, xh, s0h);
  s1l = fmaf(rt, xl, s1l); s1h = fmaf(rt, xh, s1h);
  s2l = fmaf(ra, xl, s2l); s2h = fmaf(ra, xh, s2h);
  aST[(size_t)d * 64 + lane] = packbf2(s0l, s0h);
  aTS[(size_t)d * 64 + lane] = packbf2(s1l, s1h);
  aAL[(size_t)d * 64 + lane] = packbf2(s2l, s2h);
}

// ---------------- fused layer-1 GEMM: h1 = relu([aST@Wst | aTS@Wts | aAL@W1] + b) ----------------
// h1 bf16 [N,192], layout [st|ts|all] (matches W2 row order).
__global__ __launch_bounds__(256) void k_mgemm1f(const unsigned short* __restrict__ A0,
                                                 const unsigned short* __restrict__ A1,
                                                 const unsigned short* __restrict__ A2,
                                                 const bfvec8* __restrict__ W0,
                                                 const bfvec8* __restrict__ W1f,
                                                 const bfvec8* __restrict__ W2f,
                                                 const float* __restrict__ b0,
                                                 const float* __restrict__ b1p,
                                                 const float* __restrict__ b2p,
                                                 unsigned short* __restrict__ O) {
  int wid = threadIdx.x >> 6, lane = threadIdx.x & 63;
  int rt = blockIdx.x * 4 + wid;
  if (rt >= NN / 16) return;
  int r0 = rt * 16, row = lane & 15, hi = lane >> 4;
  #pragma unroll
  for (int b = 0; b < 3; ++b) {
    const unsigned short* Ab = (b == 0 ? A0 : b == 1 ? A1 : A2) + (size_t)(r0 + row) * 128 + hi * 8;
    const bfvec8* Wb = (b == 0 ? W0 : b == 1 ? W1f : W2f);
    const float* bb = (b == 0 ? b0 : b == 1 ? b1p : b2p);
    bfvec8 af[4];
    #pragma unroll
    for (int t = 0; t < 4; ++t) af[t] = *(const bfvec8*)(Ab + t * 32);
    #pragma unroll
    for (int ct = 0; ct < 4; ++ct) {
      fvec4 acc = {0.f, 0.f, 0.f, 0.f};
      #pragma unroll
      for (int t = 0; t < 4; ++t)
        acc = __builtin_amdgcn_mfma_f32_16x16x32_bf16(af[t], Wb[(ct * 4 + t) * 64 + lane],
                                                      acc, 0, 0, 0);
      float bv = bb[ct * 16 + row];
      #pragma unroll
      for (int r = 0; r < 4; ++r)
        O[(size_t)(r0 + hi * 4 + r) * 192 + b * 64 + ct * 16 + row] =
            bf16r(fmaxf(acc[r] + bv, 0.f));
    }
  }
}

// ---------------- MFMA GEMM: O[N,NC] = A[N,K](bf16) @ Wf(bf16 frags) ----------------
// OM: 0 = fp32 out [N,NC]; 1 = bf16 out [N,NC].
template <int K, int NC, int OM>
__global__ __launch_bounds__(256) void k_mgemm(const unsigned short* __restrict__ A,
                                               const bfvec8* __restrict__ Wf,
                                               void* __restrict__ Op) {
  constexpr int KS = K / 32, NCT = NC / 16;
  int wid = threadIdx.x >> 6, lane = threadIdx.x & 63;
  int rt = blockIdx.x * 4 + wid;
  if (rt >= NN / 16) return;
  int r0 = rt * 16;
  int row = lane & 15, hi = lane >> 4;
  bfvec8 af[KS];
  const unsigned short* Ab = A + (size_t)(r0 + row) * K + hi * 8;
  #pragma unroll
  for (int t = 0; t < KS; ++t) af[t] = *(const bfvec8*)(Ab + t * 32);
  #pragma unroll
  for (int c = 0; c < NCT; ++c) {
    fvec4 acc = {0.f, 0.f, 0.f, 0.f};
    #pragma unroll
    for (int t = 0; t < KS; ++t)
      acc = __builtin_amdgcn_mfma_f32_16x16x32_bf16(af[t], Wf[(c * KS + t) * 64 + lane],
                                                    acc, 0, 0, 0);
    if constexpr (OM == 0) {
      float* O = (float*)Op;
      #pragma unroll
      for (int r = 0; r < 4; ++r)
        O[(size_t)(r0 + hi * 4 + r) * NC + c * 16 + row] = acc[r];
    } else {
      unsigned short* O = (unsigned short*)Op;
      #pragma unroll
      for (int r = 0; r < 4; ++r)
        O[(size_t)(r0 + hi * 4 + r) * NC + c * 16 + row] = bf16r(acc[r]);
    }
  }
}

// ---------------- layer-2 aggregation: T2' bf16 [N,128], unroll x4 ----------------
__global__ __launch_bounds__(256) void k_agg2(const unsigned* __restrict__ roff,
                                              const uint2* __restrict__ E,
                                              const float4* __restrict__ dinv4,
                                              const unsigned* __restrict__ Tb,
                                              const float* __restrict__ b2,
                                              unsigned* __restrict__ h2) {
  int wid = threadIdx.x >> 6;
  int lane = threadIdx.x & 63;
  int d = blockIdx.x * 4 + wid;
  if (d >= NN) return;
  unsigned ro = roff[d], re = roff[d + 1];
  float sl = 0.f, sh = 0.f;
  unsigned i = ro;
#define A2_EDGE(e, u)                                   \
  {                                                     \
    float cA = __high2float(*(const __half2*)&e.y);     \
    sl = fmaf(cA, bflo(u), sl);                         \
    sh = fmaf(cA, bfhi(u), sh);                         \
  }
  for (; i + 4 <= re; i += 4) {
    uint2 e0 = E[i], e1 = E[i + 1], e2 = E[i + 2], e3 = E[i + 3];
    unsigned u0 = Tb[(size_t)(e0.x & 0x7FFFFFFFu) * 64 + lane];
    unsigned u1 = Tb[(size_t)(e1.x & 0x7FFFFFFFu) * 64 + lane];
    unsigned u2 = Tb[(size_t)(e2.x & 0x7FFFFFFFu) * 64 + lane];
    unsigned u3 = Tb[(size_t)(e3.x & 0x7FFFFFFFu) * 64 + lane];
    A2_EDGE(e0, u0) A2_EDGE(e1, u1) A2_EDGE(e2, u2) A2_EDGE(e3, u3)
  }
  for (; i < re; ++i) {
    uint2 e = E[i];
    unsigned u = Tb[(size_t)(e.x & 0x7FFFFFFFu) * 64 + lane];
    A2_EDGE(e, u)
  }
#undef A2_EDGE
  float dz = dinv4[d].z;
  float ra = dz * dz;
  unsigned u = Tb[(size_t)d * 64 + lane];
  sl = fmaf(ra, bflo(u), sl); sh = fmaf(ra, bfhi(u), sh);
  float2 bb = ((const float2*)b2)[lane];
  sl += bb.x; sh += bb.y;
  h2[(size_t)d * 64 + lane] = packbf2(sl, sh);
}

// ---------------- layer-3 aggregation + log_softmax: T3 fp32 [N,16], unroll x4 ----------------
__global__ __launch_bounds__(256) void k_agg3(const unsigned* __restrict__ roff,
                                              const uint2* __restrict__ E,
                                              const float4* __restrict__ dinv4,
                                              const float* __restrict__ T,
                                              const float* __restrict__ b3,
                                              float* __restrict__ out) {
  int g = threadIdx.x >> 4;
  int l = threadIdx.x & 15;
  int d = blockIdx.x * 16 + g;
  if (d >= NN) return;
  unsigned ro = roff[d], re = roff[d + 1];
  float a = 0.f;
  unsigned i = ro;
  for (; i + 4 <= re; i += 4) {
    uint2 e0 = E[i], e1 = E[i + 1], e2 = E[i + 2], e3 = E[i + 3];
    float t0 = T[(size_t)(e0.x & 0x7FFFFFFFu) * 16 + l];
    float t1 = T[(size_t)(e1.x & 0x7FFFFFFFu) * 16 + l];
    float t2 = T[(size_t)(e2.x & 0x7FFFFFFFu) * 16 + l];
    float t3 = T[(size_t)(e3.x & 0x7FFFFFFFu) * 16 + l];
    a = fmaf(__high2float(*(const __half2*)&e0.y), t0, a);
    a = fmaf(__high2float(*(const __half2*)&e1.y), t1, a);
    a = fmaf(__high2float(*(const __half2*)&e2.y), t2, a);
    a = fmaf(__high2float(*(const __half2*)&e3.y), t3, a);
  }
  for (; i < re; ++i) {
    uint2 e = E[i];
    a = fmaf(__high2float(*(const __half2*)&e.y),
             T[(size_t)(e.x & 0x7FFFFFFFu) * 16 + l], a);
  }
  float dz = dinv4[d].z;
  a = fmaf(dz * dz, T[(size_t)d * 16 + l], a) + b3[l];
  float m = a;
  #pragma unroll
  for (int o = 8; o > 0; o >>= 1) m = fmaxf(m, __shfl_xor(m, o, 16));
  float ex = expf(a - m);
  float sm = ex;
  #pragma unroll
  for (int o = 8; o > 0; o >>= 1) sm += __shfl_xor(sm, o, 16);
  out[(size_t)d * 16 + l] = a - m - logf(sm);
}

// ---------------- host-side launch ----------------
extern "C" void kernel_launch(void* const* d_in, const int* in_sizes, int n_in,
                              void* d_out, int out_size, void* d_ws, size_t ws_size,
                              hipStream_t stream) {
  const float* x   = (const float*)d_in[0];
  const int* ei    = (const int*)d_in[1];
  const int* srcp  = ei;
  const int* dstp  = ei + NE;
  const int* revp  = (const int*)d_in[2];
  const float* Wst = (const float*)d_in[3];
  const float* bst = (const float*)d_in[4];
  const float* Wts = (const float*)d_in[5];
  const float* bts = (const float*)d_in[6];
  const float* W1  = (const float*)d_in[7];
  const float* b1  = (const float*)d_in[8];
  const float* W2  = (const float*)d_in[9];
  const float* b2  = (const float*)d_in[10];
  const float* W3  = (const float*)d_in[11];
  const float* b3  = (const float*)d_in[12];
  float* out = (float*)d_out;

  char* ws = (char*)d_ws;
  size_t off = 0;
  auto alloc = [&](size_t bytes) -> void* {
    off = (off + 255) & ~size_t(255);
    void* p = ws + off;
    off += bytes;
    return p;
  };
  unsigned* cnt    = (unsigned*)alloc(sizeof(unsigned) * NN);
  unsigned* roff   = (unsigned*)alloc(sizeof(unsigned) * (NN + 1));
  unsigned* cursor = (unsigned*)alloc(sizeof(unsigned) * NN);
  unsigned* bsums  = (unsigned*)alloc(sizeof(unsigned) * 128);
  float4*   dinv4  = (float4*)alloc(sizeof(float4) * NN);
  uint2*    ecsr   = (uint2*)alloc(sizeof(uint2) * NE);  // 12.8 MB
  // bufX: 25.6 MB (aggST bf16 [N,128]; later T2' bf16 [N,128] and T3 fp32 [N,16])
  char*     bufX   = (char*)alloc((size_t)NN * 128 * 2);
  unsigned* aggTS  = (unsigned*)alloc(sizeof(unsigned) * (size_t)NN * 64);  // 25.6 MB
  unsigned* aggAL  = (unsigned*)alloc(sizeof(unsigned) * (size_t)NN * 64);  // 25.6 MB
  // bufY: 38.4 MB (h1 bf16 [N,192]; later h2 bf16 [N,128])
  char*     bufY   = (char*)alloc((size_t)NN * 192 * 2);
  // xb: 25.6 MB (x in bf16 row-major [N,128])
  unsigned short* xb = (unsigned short*)alloc((size_t)NN * 128 * 2);
  uint4*    WfS    = (uint4*)alloc(sizeof(uint4) * 4 * 4 * 64);
  uint4*    WfT    = (uint4*)alloc(sizeof(uint4) * 4 * 4 * 64);
  uint4*    Wf1    = (uint4*)alloc(sizeof(uint4) * 4 * 4 * 64);
  uint4*    Wf2    = (uint4*)alloc(sizeof(uint4) * 8 * 6 * 64);
  uint4*    Wf3    = (uint4*)alloc(sizeof(uint4) * 1 * 4 * 64);
  (void)ws_size; (void)in_sizes; (void)n_in; (void)out_size;

  const int nbN = (NN + 255) / 256;
  const int nbE = (NE + 255) / 256;
  const int nbM = (NN / 16 + 3) / 4;  // MFMA gemm blocks (4 waves x 16-row tiles)

  // CSR + degree + coefficient build
  hipLaunchKernelGGL(k_zero, dim3(nbN), dim3(256), 0, stream, cnt, NN);
  hipLaunchKernelGGL(k_deg, dim3(nbE), dim3(256), 0, stream, dstp, revp, cnt);
  hipLaunchKernelGGL(k_scan1, dim3(NB_SCAN), dim3(256), 0, stream, cnt, bsums);
  hipLaunchKernelGGL(k_scan2, dim3(1), dim3(128), 0, stream, bsums);
  hipLaunchKernelGGL(k_scan3, dim3(NB_SCAN), dim3(256), 0, stream, cnt, bsums, roff, cursor);
  hipLaunchKernelGGL(k_dinv, dim3(nbN), dim3(256), 0, stream, cnt, dinv4);
  hipLaunchKernelGGL(k_csr, dim3(nbE), dim3(256), 0, stream, srcp, dstp, revp, dinv4, cursor, ecsr);

  // Weight packing + x conversion
  hipLaunchKernelGGL((k_packWf<128, 64>), dim3(4), dim3(256), 0, stream, Wst, WfS);
  hipLaunchKernelGGL((k_packWf<128, 64>), dim3(4), dim3(256), 0, stream, Wts, WfT);
  hipLaunchKernelGGL((k_packWf<128, 64>), dim3(4), dim3(256), 0, stream, W1, Wf1);
  hipLaunchKernelGGL((k_packWf<192, 128>), dim3(12), dim3(256), 0, stream, W2, Wf2);
  hipLaunchKernelGGL((k_packWf<128, 16>), dim3(1), dim3(256), 0, stream, W3, Wf3);
  hipLaunchKernelGGL(k_cvt, dim3(NN * 128 / 4 / 256), dim3(256), 0, stream,
                     (const float4*)x, (uint2*)xb, NN * 128 / 4);

  // Layer 1: aggregate x under 3 masks, then fused block GEMM + bias + relu
  hipLaunchKernelGGL(k_agg0, dim3(NN / 4), dim3(256), 0, stream,
                     roff, ecsr, dinv4, (const unsigned*)xb,
                     (unsigned*)bufX, aggTS, aggAL);
  hipLaunchKernelGGL(k_mgemm1f, dim3(nbM), dim3(256), 0, stream,
                     (const unsigned short*)bufX, (const unsigned short*)aggTS,
                     (const unsigned short*)aggAL,
                     (const bfvec8*)WfS, (const bfvec8*)WfT, (const bfvec8*)Wf1,
                     bst, bts, b1, (unsigned short*)bufY);

  // Layer 2: T2' = h1 @ Wf2 -> bufX (bf16 [N,128]); agg -> bufY (h2 bf16 [N,128])
  hipLaunchKernelGGL((k_mgemm<192, 128, 1>), dim3(nbM), dim3(256), 0, stream,
                     (const unsigned short*)bufY, (const bfvec8*)Wf2, bufX);
  hipLaunchKernelGGL(k_agg2, dim3(NN / 4), dim3(256), 0, stream,
                     roff, ecsr, dinv4, (const unsigned*)bufX, b2, (unsigned*)bufY);

  // Layer 3: T3 = h2 @ Wf3 -> bufX fp32 [N,16]; agg + log_softmax -> out
  hipLaunchKernelGGL((k_mgemm<128, 16, 0>), dim3(nbM), dim3(256), 0, stream,
                     (const unsigned short*)bufY, (const bfvec8*)Wf3, bufX);
  hipLaunchKernelGGL(k_agg3, dim3(NN / 16), dim3(256), 0, stream,
                     roff, ecsr, dinv4, (const float*)bufX, b3, out);
}

// Round 13
// 507.136 us; speedup vs baseline: 1.8154x; 1.0943x over previous
//
#include <hip/hip_runtime.h>
#include <hip/hip_fp16.h>
#include <math.h>

static constexpr int NN = 100000;   // nodes
static constexpr int NE = 1600000;  // edges
static constexpr int NB_SCAN = (NN + 1023) / 1024;  // 98 scan blocks
static constexpr int NB_E = (NE + 255) / 256;       // 6250 edge blocks
static constexpr int N4 = NN * 128 / 4;             // 3.2M float4s in x
static constexpr int NB_CVT = (N4 + 255) / 256;     // 12500 cvt blocks

typedef __attribute__((ext_vector_type(8))) short bfvec8;  // 8 bf16 = 4 VGPRs
typedef __attribute__((ext_vector_type(4))) float fvec4;   // MFMA accumulator

// ---------------- bf16 helpers (fp32 <-> bf16 bit ops) ----------------
__device__ __forceinline__ float bflo(unsigned u) { return __uint_as_float(u << 16); }
__device__ __forceinline__ float bfhi(unsigned u) { return __uint_as_float(u & 0xFFFF0000u); }
__device__ __forceinline__ unsigned packbf2(float a, float b) {  // RTNE
  unsigned ua = __float_as_uint(a), ub = __float_as_uint(b);
  unsigned ra = (ua + 0x7fffu + ((ua >> 16) & 1u)) >> 16;
  unsigned rb = (ub + 0x7fffu + ((ub >> 16) & 1u)) >> 16;
  return ra | (rb << 16);
}
__device__ __forceinline__ unsigned short bf16r(float a) {  // RTNE single
  unsigned ua = __float_as_uint(a);
  return (unsigned short)((ua + 0x7fffu + ((ua >> 16) & 1u)) >> 16);
}
__device__ __forceinline__ float2 coefs(unsigned y) {  // {cB, cA} from packed half2
  return __half22float2(*(const __half2*)&y);
}

// ---------------- utility ----------------
__global__ __launch_bounds__(256) void k_zero(unsigned* __restrict__ p, int n) {
  int i = blockIdx.x * 256 + threadIdx.x;
  if (i < n) p[i] = 0u;
}

// Pack fp32 W[K][NC] into MFMA B-fragment-major bf16 (device body):
// Wf[(c*(K/32)+t)*64 + lane] = { W[t*32+(lane>>4)*8+j][c*16+(lane&15)], j=0..7 }
template <int K, int NC>
__device__ __forceinline__ void packWf_dev(const float* __restrict__ W,
                                           uint4* __restrict__ Wf, int i) {
  constexpr int TOT = (NC / 16) * (K / 32) * 64;
  if (i >= TOT) return;
  int lane = i & 63;
  int t = (i >> 6) % (K / 32);
  int c = i / ((K / 32) * 64);
  int col = c * 16 + (lane & 15);
  int k0 = t * 32 + (lane >> 4) * 8;
  float e[8];
  #pragma unroll
  for (int j = 0; j < 8; ++j) e[j] = W[(size_t)(k0 + j) * NC + col];
  Wf[i] = make_uint4(packbf2(e[0], e[1]), packbf2(e[2], e[3]),
                     packbf2(e[4], e[5]), packbf2(e[6], e[7]));
}

// ---------------- phase-1 fat kernel: deg+rank | x->bf16 cvt | weight packs ----------------
// Independent jobs dispatched by blockIdx range; cvt/packs hide under deg's atomic latency.
__global__ __launch_bounds__(256) void k_phase1(
    const int* __restrict__ dst, const int* __restrict__ rev,
    unsigned* __restrict__ cnt, unsigned short* __restrict__ rank16,
    const float4* __restrict__ X, uint2* __restrict__ Xb,
    const float* __restrict__ Wst, const float* __restrict__ Wts,
    const float* __restrict__ W1, const float* __restrict__ W2,
    const float* __restrict__ W3,
    uint4* __restrict__ WfS, uint4* __restrict__ WfT, uint4* __restrict__ Wf1,
    uint4* __restrict__ Wf2, uint4* __restrict__ Wf3) {
  int b = blockIdx.x;
  if (b < NB_E) {  // degree count + rank capture (low16 of packed count = rank)
    int e = b * 256 + threadIdx.x;
    if (e < NE) {
      unsigned add = 1u + ((rev[e] == 0) ? 0x10000u : 0u);
      unsigned old = atomicAdd(&cnt[dst[e]], add);
      rank16[e] = (unsigned short)(old & 0xFFFFu);
    }
    return;
  }
  b -= NB_E;
  if (b < NB_CVT) {  // x fp32 -> bf16
    int i = b * 256 + threadIdx.x;
    if (i < N4) {
      float4 v = X[i];
      Xb[i] = make_uint2(packbf2(v.x, v.y), packbf2(v.z, v.w));
    }
    return;
  }
  b -= NB_CVT;
  int i = threadIdx.x + (b & 3) * 256;  // within-pack index helper (256-thr blocks)
  if (b < 4)       packWf_dev<128, 64>(Wst, WfS, b * 256 + threadIdx.x);
  else if (b < 8)  packWf_dev<128, 64>(Wts, WfT, (b - 4) * 256 + threadIdx.x);
  else if (b < 12) packWf_dev<128, 64>(W1, Wf1, (b - 8) * 256 + threadIdx.x);
  else if (b < 24) packWf_dev<192, 128>(W2, Wf2, (b - 12) * 256 + threadIdx.x);
  else             packWf_dev<128, 16>(W3, Wf3, (b - 24) * 256 + threadIdx.x);
  (void)i;
}

// ---------------- scan of (cnt & 0xFFFF) ----------------
__global__ __launch_bounds__(256) void k_scan1(const unsigned* __restrict__ cnt,
                                               unsigned* __restrict__ bsums) {
  int g = blockIdx.x, t = threadIdx.x;
  int base = g * 1024 + t * 4;
  unsigned s = 0;
  #pragma unroll
  for (int j = 0; j < 4; ++j) {
    int i = base + j;
    if (i < NN) s += cnt[i] & 0xFFFFu;
  }
  __shared__ unsigned sm[256];
  sm[t] = s;
  __syncthreads();
  for (int o = 128; o > 0; o >>= 1) {
    if (t < o) sm[t] += sm[t + o];
    __syncthreads();
  }
  if (t == 0) bsums[g] = sm[0];
}

__global__ __launch_bounds__(128) void k_scan2(unsigned* __restrict__ bsums) {
  __shared__ unsigned sm[128];
  int t = threadIdx.x;
  unsigned v = (t < NB_SCAN) ? bsums[t] : 0u;
  sm[t] = v;
  __syncthreads();
  for (int o = 1; o < 128; o <<= 1) {
    unsigned u = (t >= o) ? sm[t - o] : 0u;
    __syncthreads();
    sm[t] += u;
    __syncthreads();
  }
  if (t < NB_SCAN) bsums[t] = sm[t] - v;  // exclusive
}

__global__ __launch_bounds__(256) void k_scan3(const unsigned* __restrict__ cnt,
                                               const unsigned* __restrict__ bsums,
                                               unsigned* __restrict__ roff) {
  int g = blockIdx.x, t = threadIdx.x;
  int base = g * 1024 + t * 4;
  unsigned v[4];
  unsigned tsum = 0;
  #pragma unroll
  for (int j = 0; j < 4; ++j) {
    int i = base + j;
    v[j] = (i < NN) ? (cnt[i] & 0xFFFFu) : 0u;
    tsum += v[j];
  }
  __shared__ unsigned sm[256];
  sm[t] = tsum;
  __syncthreads();
  for (int o = 1; o < 256; o <<= 1) {
    unsigned u = (t >= o) ? sm[t - o] : 0u;
    __syncthreads();
    sm[t] += u;
    __syncthreads();
  }
  unsigned run = bsums[g] + sm[t] - tsum;  // exclusive prefix for this thread
  #pragma unroll
  for (int j = 0; j < 4; ++j) {
    int i = base + j;
    if (i < NN) {
      roff[i] = run;
      run += v[j];
      if (i == NN - 1) roff[NN] = run;
    }
  }
}

// dinv4[n] = {rsqrt(deg_st), rsqrt(deg_ts), rsqrt(deg_all), 0}
__global__ __launch_bounds__(256) void k_dinv(const unsigned* __restrict__ cnt,
                                              float4* __restrict__ dinv4) {
  int n = blockIdx.x * 256 + threadIdx.x;
  if (n >= NN) return;
  unsigned c = cnt[n];
  float all = (float)(c & 0xFFFFu) + 1.0f;
  float st = (float)(c >> 16) + 1.0f;
  float ts = all - st + 1.0f;
  dinv4[n] = make_float4(rsqrtf(st), rsqrtf(ts), rsqrtf(all), 0.0f);
}

// CSR fill, atomic-free: p = roff[dst] + rank16[e].
// ecsr[p] = {src | rev<<31, half2(cB, cA)}
__global__ __launch_bounds__(256) void k_csr(const int* __restrict__ src,
                                             const int* __restrict__ dst,
                                             const int* __restrict__ rev,
                                             const unsigned short* __restrict__ rank16,
                                             const unsigned* __restrict__ roff,
                                             const float4* __restrict__ dinv4,
                                             uint2* __restrict__ ecsr) {
  int e = blockIdx.x * 256 + threadIdx.x;
  if (e >= NE) return;
  int s = src[e], d = dst[e];
  int r = rev[e];
  float4 sv = dinv4[s];
  float4 dv = dinv4[d];
  float cB = r ? (sv.y * dv.y) : (sv.x * dv.x);
  float cA = sv.z * dv.z;
  __half2 h = __floats2half2_rn(cB, cA);
  unsigned p = roff[d] + rank16[e];
  ecsr[p] = make_uint2((unsigned)s | (r ? 0x80000000u : 0u), *(const unsigned*)&h);
}

// ---------------- layer-1 edge aggregation over x (bf16 [N,128]) ----------------
// One wave per node; lane holds cols {2*lane, 2*lane+1}.
// Unroll x4: 4 independent ecsr loads then 4 independent 256B gathers per chain-step.
__global__ __launch_bounds__(256) void k_agg0(const unsigned* __restrict__ roff,
                                              const uint2* __restrict__ E,
                                              const float4* __restrict__ dinv4,
                                              const unsigned* __restrict__ Xb,
                                              unsigned* __restrict__ aST,
                                              unsigned* __restrict__ aTS,
                                              unsigned* __restrict__ aAL) {
  int wid = threadIdx.x >> 6;
  int lane = threadIdx.x & 63;
  int d = blockIdx.x * 4 + wid;
  if (d >= NN) return;
  unsigned ro = roff[d], re = roff[d + 1];
  float s0l = 0.f, s0h = 0.f, s1l = 0.f, s1h = 0.f, s2l = 0.f, s2h = 0.f;
  unsigned i = ro;
#define A0_EDGE(e, u)                                              \
  {                                                                \
    float2 c = coefs(e.y);                                         \
    bool ts = (e.x & 0x80000000u) != 0;                            \
    float cB0 = ts ? 0.f : c.x;                                    \
    float cB1 = ts ? c.x : 0.f;                                    \
    float xl = bflo(u), xh = bfhi(u);                              \
    s2l = fmaf(c.y, xl, s2l); s2h = fmaf(c.y, xh, s2h);            \
    s0l = fmaf(cB0, xl, s0l); s0h = fmaf(cB0, xh, s0h);            \
    s1l = fmaf(cB1, xl, s1l); s1h = fmaf(cB1, xh, s1h);            \
  }
  for (; i + 4 <= re; i += 4) {
    uint2 e0 = E[i], e1 = E[i + 1], e2 = E[i + 2], e3 = E[i + 3];
    unsigned u0 = Xb[(size_t)(e0.x & 0x7FFFFFFFu) * 64 + lane];
    unsigned u1 = Xb[(size_t)(e1.x & 0x7FFFFFFFu) * 64 + lane];
    unsigned u2 = Xb[(size_t)(e2.x & 0x7FFFFFFFu) * 64 + lane];
    unsigned u3 = Xb[(size_t)(e3.x & 0x7FFFFFFFu) * 64 + lane];
    A0_EDGE(e0, u0) A0_EDGE(e1, u1) A0_EDGE(e2, u2) A0_EDGE(e3, u3)
  }
  for (; i < re; ++i) {
    uint2 e = E[i];
    unsigned u = Xb[(size_t)(e.x & 0x7FFFFFFFu) * 64 + lane];
    A0_EDGE(e, u)
  }
#undef A0_EDGE
  // self-loop terms: dinv^2 * x_d per mask
  float4 dv = dinv4[d];
  unsigned u = Xb[(size_t)d * 64 + lane];
  float xl = bflo(u), xh = bfhi(u);
  float rs = dv.x * dv.x, rt = dv.y * dv.y, ra = dv.z * dv.z;
  s0l = fmaf(rs, xl, s0l); s0h = fmaf(rs, xh, s0h);
  s1l = fmaf(rt, xl, s1l); s1h = fmaf(rt, xh, s1h);
  s2l = fmaf(ra, xl, s2l); s2h = fmaf(ra, xh, s2h);
  aST[(size_t)d * 64 + lane] = packbf2(s0l, s0h);
  aTS[(size_t)d * 64 + lane] = packbf2(s1l, s1h);
  aAL[(size_t)d * 64 + lane] = packbf2(s2l, s2h);
}

// ---------------- fused layer-1 GEMM: h1 = relu([aST@Wst | aTS@Wts | aAL@W1] + b) ----------------
// h1 bf16 [N,192], layout [st|ts|all] (matches W2 row order).
__global__ __launch_bounds__(256) void k_mgemm1f(const unsigned short* __restrict__ A0,
                                                 const unsigned short* __restrict__ A1,
                                                 const unsigned short* __restrict__ A2,
                                                 const bfvec8* __restrict__ W0,
                                                 const bfvec8* __restrict__ W1f,
                                                 const bfvec8* __restrict__ W2f,
                                                 const float* __restrict__ b0,
                                                 const float* __restrict__ b1p,
                                                 const float* __restrict__ b2p,
                                                 unsigned short* __restrict__ O) {
  int wid = threadIdx.x >> 6, lane = threadIdx.x & 63;
  int rt = blockIdx.x * 4 + wid;
  if (rt >= NN / 16) return;
  int r0 = rt * 16, row = lane & 15, hi = lane >> 4;
  #pragma unroll
  for (int b = 0; b < 3; ++b) {
    const unsigned short* Ab = (b == 0 ? A0 : b == 1 ? A1 : A2) + (size_t)(r0 + row) * 128 + hi * 8;
    const bfvec8* Wb = (b == 0 ? W0 : b == 1 ? W1f : W2f);
    const float* bb = (b == 0 ? b0 : b == 1 ? b1p : b2p);
    bfvec8 af[4];
    #pragma unroll
    for (int t = 0; t < 4; ++t) af[t] = *(const bfvec8*)(Ab + t * 32);
    #pragma unroll
    for (int ct = 0; ct < 4; ++ct) {
      fvec4 acc = {0.f, 0.f, 0.f, 0.f};
      #pragma unroll
      for (int t = 0; t < 4; ++t)
        acc = __builtin_amdgcn_mfma_f32_16x16x32_bf16(af[t], Wb[(ct * 4 + t) * 64 + lane],
                                                      acc, 0, 0, 0);
      float bv = bb[ct * 16 + row];
      #pragma unroll
      for (int r = 0; r < 4; ++r)
        O[(size_t)(r0 + hi * 4 + r) * 192 + b * 64 + ct * 16 + row] =
            bf16r(fmaxf(acc[r] + bv, 0.f));
    }
  }
}

// ---------------- MFMA GEMM: O[N,NC] = A[N,K](bf16) @ Wf(bf16 frags) ----------------
// OM: 0 = fp32 out [N,NC]; 1 = bf16 out [N,NC].
template <int K, int NC, int OM>
__global__ __launch_bounds__(256) void k_mgemm(const unsigned short* __restrict__ A,
                                               const bfvec8* __restrict__ Wf,
                                               void* __restrict__ Op) {
  constexpr int KS = K / 32, NCT = NC / 16;
  int wid = threadIdx.x >> 6, lane = threadIdx.x & 63;
  int rt = blockIdx.x * 4 + wid;
  if (rt >= NN / 16) return;
  int r0 = rt * 16;
  int row = lane & 15, hi = lane >> 4;
  bfvec8 af[KS];
  const unsigned short* Ab = A + (size_t)(r0 + row) * K + hi * 8;
  #pragma unroll
  for (int t = 0; t < KS; ++t) af[t] = *(const bfvec8*)(Ab + t * 32);
  #pragma unroll
  for (int c = 0; c < NCT; ++c) {
    fvec4 acc = {0.f, 0.f, 0.f, 0.f};
    #pragma unroll
    for (int t = 0; t < KS; ++t)
      acc = __builtin_amdgcn_mfma_f32_16x16x32_bf16(af[t], Wf[(c * KS + t) * 64 + lane],
                                                    acc, 0, 0, 0);
    if constexpr (OM == 0) {
      float* O = (float*)Op;
      #pragma unroll
      for (int r = 0; r < 4; ++r)
        O[(size_t)(r0 + hi * 4 + r) * NC + c * 16 + row] = acc[r];
    } else {
      unsigned short* O = (unsigned short*)Op;
      #pragma unroll
      for (int r = 0; r < 4; ++r)
        O[(size_t)(r0 + hi * 4 + r) * NC + c * 16 + row] = bf16r(acc[r]);
    }
  }
}

// ---------------- layer-2 aggregation: T2' bf16 [N,128], unroll x4 ----------------
__global__ __launch_bounds__(256) void k_agg2(const unsigned* __restrict__ roff,
                                              const uint2* __restrict__ E,
                                              const float4* __restrict__ dinv4,
                                              const unsigned* __restrict__ Tb,
                                              const float* __restrict__ b2,
                                              unsigned* __restrict__ h2) {
  int wid = threadIdx.x >> 6;
  int lane = threadIdx.x & 63;
  int d = blockIdx.x * 4 + wid;
  if (d >= NN) return;
  unsigned ro = roff[d], re = roff[d + 1];
  float sl = 0.f, sh = 0.f;
  unsigned i = ro;
#define A2_EDGE(e, u)                                   \
  {                                                     \
    float cA = __high2float(*(const __half2*)&e.y);     \
    sl = fmaf(cA, bflo(u), sl);                         \
    sh = fmaf(cA, bfhi(u), sh);                         \
  }
  for (; i + 4 <= re; i += 4) {
    uint2 e0 = E[i], e1 = E[i + 1], e2 = E[i + 2], e3 = E[i + 3];
    unsigned u0 = Tb[(size_t)(e0.x & 0x7FFFFFFFu) * 64 + lane];
    unsigned u1 = Tb[(size_t)(e1.x & 0x7FFFFFFFu) * 64 + lane];
    unsigned u2 = Tb[(size_t)(e2.x & 0x7FFFFFFFu) * 64 + lane];
    unsigned u3 = Tb[(size_t)(e3.x & 0x7FFFFFFFu) * 64 + lane];
    A2_EDGE(e0, u0) A2_EDGE(e1, u1) A2_EDGE(e2, u2) A2_EDGE(e3, u3)
  }
  for (; i < re; ++i) {
    uint2 e = E[i];
    unsigned u = Tb[(size_t)(e.x & 0x7FFFFFFFu) * 64 + lane];
    A2_EDGE(e, u)
  }
#undef A2_EDGE
  float dz = dinv4[d].z;
  float ra = dz * dz;
  unsigned u = Tb[(size_t)d * 64 + lane];
  sl = fmaf(ra, bflo(u), sl); sh = fmaf(ra, bfhi(u), sh);
  float2 bb = ((const float2*)b2)[lane];
  sl += bb.x; sh += bb.y;
  h2[(size_t)d * 64 + lane] = packbf2(sl, sh);
}

// ---------------- layer-3 aggregation + log_softmax: T3 fp32 [N,16], unroll x4 ----------------
__global__ __launch_bounds__(256) void k_agg3(const unsigned* __restrict__ roff,
                                              const uint2* __restrict__ E,
                                              const float4* __restrict__ dinv4,
                                              const float* __restrict__ T,
                                              const float* __restrict__ b3,
                                              float* __restrict__ out) {
  int g = threadIdx.x >> 4;
  int l = threadIdx.x & 15;
  int d = blockIdx.x * 16 + g;
  if (d >= NN) return;
  unsigned ro = roff[d], re = roff[d + 1];
  float a = 0.f;
  unsigned i = ro;
  for (; i + 4 <= re; i += 4) {
    uint2 e0 = E[i], e1 = E[i + 1], e2 = E[i + 2], e3 = E[i + 3];
    float t0 = T[(size_t)(e0.x & 0x7FFFFFFFu) * 16 + l];
    float t1 = T[(size_t)(e1.x & 0x7FFFFFFFu) * 16 + l];
    float t2 = T[(size_t)(e2.x & 0x7FFFFFFFu) * 16 + l];
    float t3 = T[(size_t)(e3.x & 0x7FFFFFFFu) * 16 + l];
    a = fmaf(__high2float(*(const __half2*)&e0.y), t0, a);
    a = fmaf(__high2float(*(const __half2*)&e1.y), t1, a);
    a = fmaf(__high2float(*(const __half2*)&e2.y), t2, a);
    a = fmaf(__high2float(*(const __half2*)&e3.y), t3, a);
  }
  for (; i < re; ++i) {
    uint2 e = E[i];
    a = fmaf(__high2float(*(const __half2*)&e.y),
             T[(size_t)(e.x & 0x7FFFFFFFu) * 16 + l], a);
  }
  float dz = dinv4[d].z;
  a = fmaf(dz * dz, T[(size_t)d * 16 + l], a) + b3[l];
  float m = a;
  #pragma unroll
  for (int o = 8; o > 0; o >>= 1) m = fmaxf(m, __shfl_xor(m, o, 16));
  float ex = expf(a - m);
  float sm = ex;
  #pragma unroll
  for (int o = 8; o > 0; o >>= 1) sm += __shfl_xor(sm, o, 16);
  out[(size_t)d * 16 + l] = a - m - logf(sm);
}

// ---------------- host-side launch ----------------
extern "C" void kernel_launch(void* const* d_in, const int* in_sizes, int n_in,
                              void* d_out, int out_size, void* d_ws, size_t ws_size,
                              hipStream_t stream) {
  const float* x   = (const float*)d_in[0];
  const int* ei    = (const int*)d_in[1];
  const int* srcp  = ei;
  const int* dstp  = ei + NE;
  const int* revp  = (const int*)d_in[2];
  const float* Wst = (const float*)d_in[3];
  const float* bst = (const float*)d_in[4];
  const float* Wts = (const float*)d_in[5];
  const float* bts = (const float*)d_in[6];
  const float* W1  = (const float*)d_in[7];
  const float* b1  = (const float*)d_in[8];
  const float* W2  = (const float*)d_in[9];
  const float* b2  = (const float*)d_in[10];
  const float* W3  = (const float*)d_in[11];
  const float* b3  = (const float*)d_in[12];
  float* out = (float*)d_out;

  char* ws = (char*)d_ws;
  size_t off = 0;
  auto alloc = [&](size_t bytes) -> void* {
    off = (off + 255) & ~size_t(255);
    void* p = ws + off;
    off += bytes;
    return p;
  };
  unsigned* cnt    = (unsigned*)alloc(sizeof(unsigned) * NN);
  unsigned* roff   = (unsigned*)alloc(sizeof(unsigned) * (NN + 1));
  unsigned* bsums  = (unsigned*)alloc(sizeof(unsigned) * 128);
  unsigned short* rank16 = (unsigned short*)alloc(sizeof(unsigned short) * NE);  // 3.2 MB
  float4*   dinv4  = (float4*)alloc(sizeof(float4) * NN);
  uint2*    ecsr   = (uint2*)alloc(sizeof(uint2) * NE);  // 12.8 MB
  // bufX: 25.6 MB (aggST bf16 [N,128]; later T2' bf16 [N,128] and T3 fp32 [N,16])
  char*     bufX   = (char*)alloc((size_t)NN * 128 * 2);
  unsigned* aggTS  = (unsigned*)alloc(sizeof(unsigned) * (size_t)NN * 64);  // 25.6 MB
  unsigned* aggAL  = (unsigned*)alloc(sizeof(unsigned) * (size_t)NN * 64);  // 25.6 MB
  // bufY: 38.4 MB (h1 bf16 [N,192]; later h2 bf16 [N,128])
  char*     bufY   = (char*)alloc((size_t)NN * 192 * 2);
  // xb: 25.6 MB (x in bf16 row-major [N,128])
  unsigned short* xb = (unsigned short*)alloc((size_t)NN * 128 * 2);
  uint4*    WfS    = (uint4*)alloc(sizeof(uint4) * 4 * 4 * 64);
  uint4*    WfT    = (uint4*)alloc(sizeof(uint4) * 4 * 4 * 64);
  uint4*    Wf1    = (uint4*)alloc(sizeof(uint4) * 4 * 4 * 64);
  uint4*    Wf2    = (uint4*)alloc(sizeof(uint4) * 8 * 6 * 64);
  uint4*    Wf3    = (uint4*)alloc(sizeof(uint4) * 1 * 4 * 64);
  (void)ws_size; (void)in_sizes; (void)n_in; (void)out_size;

  const int nbN = (NN + 255) / 256;
  const int nbM = (NN / 16 + 3) / 4;  // MFMA gemm blocks (4 waves x 16-row tiles)
  const int nbP1 = NB_E + NB_CVT + 25;  // fat phase-1 grid

  // Phase 0: zero degree counters
  hipLaunchKernelGGL(k_zero, dim3(nbN), dim3(256), 0, stream, cnt, NN);
  // Phase 1 (fat): deg+rank | x->bf16 | weight packs
  hipLaunchKernelGGL(k_phase1, dim3(nbP1), dim3(256), 0, stream,
                     dstp, revp, cnt, rank16, (const float4*)x, (uint2*)xb,
                     Wst, Wts, W1, W2, W3, WfS, WfT, Wf1, Wf2, Wf3);
  // Scan + dinv
  hipLaunchKernelGGL(k_scan1, dim3(NB_SCAN), dim3(256), 0, stream, cnt, bsums);
  hipLaunchKernelGGL(k_scan2, dim3(1), dim3(128), 0, stream, bsums);
  hipLaunchKernelGGL(k_scan3, dim3(NB_SCAN), dim3(256), 0, stream, cnt, bsums, roff);
  hipLaunchKernelGGL(k_dinv, dim3(nbN), dim3(256), 0, stream, cnt, dinv4);
  // CSR fill (atomic-free)
  hipLaunchKernelGGL(k_csr, dim3(NB_E), dim3(256), 0, stream,
                     srcp, dstp, revp, rank16, roff, dinv4, ecsr);

  // Layer 1: aggregate x under 3 masks, then fused block GEMM + bias + relu
  hipLaunchKernelGGL(k_agg0, dim3(NN / 4), dim3(256), 0, stream,
                     roff, ecsr, dinv4, (const unsigned*)xb,
                     (unsigned*)bufX, aggTS, aggAL);
  hipLaunchKernelGGL(k_mgemm1f, dim3(nbM), dim3(256), 0, stream,
                     (const unsigned short*)bufX, (const unsigned short*)aggTS,
                     (const unsigned short*)aggAL,
                     (const bfvec8*)WfS, (const bfvec8*)WfT, (const bfvec8*)Wf1,
                     bst, bts, b1, (unsigned short*)bufY);

  // Layer 2: T2' = h1 @ Wf2 -> bufX (bf16 [N,128]); agg -> bufY (h2 bf16 [N,128])
  hipLaunchKernelGGL((k_mgemm<192, 128, 1>), dim3(nbM), dim3(256), 0, stream,
                     (const unsigned short*)bufY, (const bfvec8*)Wf2, bufX);
  hipLaunchKernelGGL(k_agg2, dim3(NN / 4), dim3(256), 0, stream,
                     roff, ecsr, dinv4, (const unsigned*)bufX, b2, (unsigned*)bufY);

  // Layer 3: T3 = h2 @ Wf3 -> bufX fp32 [N,16]; agg + log_softmax -> out
  hipLaunchKernelGGL((k_mgemm<128, 16, 0>), dim3(nbM), dim3(256), 0, stream,
                     (const unsigned short*)bufY, (const bfvec8*)Wf3, bufX);
  hipLaunchKernelGGL(k_agg3, dim3(NN / 16), dim3(256), 0, stream,
                     roff, ecsr, dinv4, (const float*)bufX, b3, out);
}